// Round 7
// baseline (660.176 us; speedup 1.0000x reference)
//
#include <hip/hip_runtime.h>
#include <math.h>

#define N_NODES 100000
#define N_EDGES 1600000
#define D 128
#define EPS 1e-5f
#define NCNT (2 * N_NODES)
#define SCAN_CHUNK 1024
#define SCAN_BLOCKS ((NCNT + SCAN_CHUNK - 1) / SCAN_CHUNK)   // 196
#define OFF_PAD (SCAN_BLOCKS * SCAN_CHUNK + 1)
#define TASKS (2 * N_NODES)

#define K0 384
#define KL 128
#define PAD0 (K0 + 8)     // bf16 elems per LDS row, layer0
#define PADL (KL + 8)     // bf16 elems per LDS row, layers 1-3
#define SSTR 132          // f32 sout row stride

// --- bucketed fill (multisplit) ---
#define BSH 8                                    // 256 tasks per bucket
#define NB ((TASKS + 255) >> BSH)                // 782 buckets
#define CHUNKE 4096                              // edges per binpass block (round-2 proven)
#define NBB ((N_EDGES + CHUNKE - 1) / CHUNKE)    // 391 blocks
#define SCAP 6144                                // scatpass LDS image capacity

typedef unsigned short ushort_t;
typedef unsigned long long ull;
typedef short short8 __attribute__((ext_vector_type(8)));     // MFMA A/B frag
typedef _Float16 half8 __attribute__((ext_vector_type(8)));   // fp16 x row chunk
typedef _Float16 half4v __attribute__((ext_vector_type(4)));
typedef float f32x4 __attribute__((ext_vector_type(4)));      // MFMA C/D frag

static __device__ __forceinline__ float bf2f(ushort_t u) {
    return __uint_as_float(((unsigned)u) << 16);
}
static __device__ __forceinline__ ushort_t f2bf(float f) {
    unsigned u = __float_as_uint(f);
    u += 0x7FFF + ((u >> 16) & 1);          // RNE
    return (ushort_t)(u >> 16);
}
static __device__ __forceinline__ float tanh_fast(float v) {
    return 1.0f - 2.0f / (__expf(2.0f * v) + 1.0f);
}

// ---------------------------------------------------------------------------
// x (f32) -> xh (fp16), 4 elems/thread.
// ---------------------------------------------------------------------------
__global__ void cvt_x_kernel(const float* __restrict__ x, _Float16* __restrict__ xh) {
    int i = blockIdx.x * blockDim.x + threadIdx.x;   // 3.2M threads
    float4 v = ((const float4*)x)[i];
    half4v h;
    h[0] = (_Float16)v.x; h[1] = (_Float16)v.y;
    h[2] = (_Float16)v.z; h[3] = (_Float16)v.w;
    ((half4v*)xh)[i] = h;
}

// ---------------------------------------------------------------------------
// CSR build: histogram + scan
// ---------------------------------------------------------------------------
__global__ void hist_kernel(const int* __restrict__ sv, const int* __restrict__ dv,
                            int* __restrict__ cnt) {
    int e = blockIdx.x * blockDim.x + threadIdx.x;
    if (e >= N_EDGES) return;
    atomicAdd(&cnt[dv[e]], 1);
    atomicAdd(&cnt[N_NODES + sv[e]], 1);
}

__global__ void scan_a(const int* __restrict__ cnt, int* __restrict__ off,
                       int* __restrict__ aux) {
    __shared__ int lds[256];
    int tid = threadIdx.x;
    int base = blockIdx.x * SCAN_CHUNK + tid * 4;
    int v0 = (base + 0 < NCNT) ? cnt[base + 0] : 0;
    int v1 = (base + 1 < NCNT) ? cnt[base + 1] : 0;
    int v2 = (base + 2 < NCNT) ? cnt[base + 2] : 0;
    int v3 = (base + 3 < NCNT) ? cnt[base + 3] : 0;
    int tot = v0 + v1 + v2 + v3;
    lds[tid] = tot;
    __syncthreads();
    for (int s = 1; s < 256; s <<= 1) {
        int add = (tid >= s) ? lds[tid - s] : 0;
        __syncthreads();
        lds[tid] += add;
        __syncthreads();
    }
    int excl = lds[tid] - tot;
    off[base + 1] = excl + v0;
    off[base + 2] = excl + v0 + v1;
    off[base + 3] = excl + v0 + v1 + v2;
    off[base + 4] = excl + tot;
    if (tid == 255) aux[blockIdx.x] = lds[255];
}

__global__ void scan_b(int* __restrict__ aux) {
    __shared__ int lds[256];
    int tid = threadIdx.x;
    int v = (tid < SCAN_BLOCKS) ? aux[tid] : 0;
    lds[tid] = v;
    __syncthreads();
    for (int s = 1; s < 256; s <<= 1) {
        int add = (tid >= s) ? lds[tid - s] : 0;
        __syncthreads();
        lds[tid] += add;
        __syncthreads();
    }
    aux[tid] = lds[tid] - v;
}

__global__ void scan_c(int* __restrict__ off, const int* __restrict__ aux) {
    int tid = threadIdx.x;
    int add = aux[blockIdx.x];
    int base = blockIdx.x * SCAN_CHUNK + tid * 4;
    off[base + 1] += add;
    off[base + 2] += add;
    off[base + 3] += add;
    off[base + 4] += add;
    if (blockIdx.x == 0 && tid == 0) off[0] = 0;
}

// bucket cursor init: bcur[b] = off[256*b]
__global__ void binit(const int* __restrict__ off, int* __restrict__ bcur) {
    int b = blockIdx.x * 256 + threadIdx.x;
    if (b < NB) bcur[b] = off[b << BSH];
}

// ---------------------------------------------------------------------------
// binpass (round-2 proven config): bin entries into per-bucket regions of
// stg (8B entries: task<<32 | w15<<17 | other).
// ---------------------------------------------------------------------------
__global__ __launch_bounds__(256, 2) void binpass(
    const int* __restrict__ sv, const int* __restrict__ dv,
    const float* __restrict__ ew, int* __restrict__ bcur,
    ull* __restrict__ stg) {
    __shared__ ull image[2 * CHUNKE];          // 64 KB
    __shared__ int histB[NB];
    __shared__ int scB[NB];
    __shared__ int gbaseB[NB];
    __shared__ int partial[256];

    int t = threadIdx.x;
    int eb0 = blockIdx.x * CHUNKE;
    int ebn = N_EDGES - eb0;
    if (ebn > CHUNKE) ebn = CHUNKE;

    for (int i = t; i < NB; i += 256) histB[i] = 0;
    __syncthreads();

    // pass 1: histogram
#pragma unroll
    for (int i = 0; i < CHUNKE / 256; ++i) {
        int k = i * 256 + t;
        if (k < ebn) {
            int e = eb0 + k;
            int s = sv[e], d = dv[e];
            atomicAdd(&histB[d >> BSH], 1);
            atomicAdd(&histB[(N_NODES + s) >> BSH], 1);
        }
    }
    __syncthreads();

    // block exclusive scan of histB[0..NB) (pad to 1024, 4 elems/thread)
    {
        int i0 = t * 4;
        int v0 = (i0 + 0 < NB) ? histB[i0 + 0] : 0;
        int v1 = (i0 + 1 < NB) ? histB[i0 + 1] : 0;
        int v2 = (i0 + 2 < NB) ? histB[i0 + 2] : 0;
        int v3 = (i0 + 3 < NB) ? histB[i0 + 3] : 0;
        int tot = v0 + v1 + v2 + v3;
        partial[t] = tot;
        __syncthreads();
        for (int s = 1; s < 256; s <<= 1) {
            int add = (t >= s) ? partial[t - s] : 0;
            __syncthreads();
            partial[t] += add;
            __syncthreads();
        }
        int excl = partial[t] - tot;
        if (i0 + 0 < NB) scB[i0 + 0] = excl;
        if (i0 + 1 < NB) scB[i0 + 1] = excl + v0;
        if (i0 + 2 < NB) scB[i0 + 2] = excl + v0 + v1;
        if (i0 + 3 < NB) scB[i0 + 3] = excl + v0 + v1 + v2;
    }
    __syncthreads();

    // reserve global segments; reset histB for reuse as running counters
    for (int i = t; i < NB; i += 256) {
        int n = histB[i];
        gbaseB[i] = (n > 0) ? atomicAdd(&bcur[i], n) : 0;
        histB[i] = 0;
    }
    __syncthreads();

    // pass 2: scatter entries into LDS image in bucket order
#pragma unroll
    for (int i = 0; i < CHUNKE / 256; ++i) {
        int k = i * 256 + t;
        if (k < ebn) {
            int e = eb0 + k;
            int s = sv[e], d = dv[e];
            float w = ew[e];
            unsigned wq = (unsigned)(w * 32768.0f + 0.5f);
            if (wq > 32767u) wq = 32767u;
            // mi entry: task = d, payload = s
            {
                int task = d, b = task >> BSH;
                int l = atomicAdd(&histB[b], 1);
                image[scB[b] + l] = ((ull)task << 32) | ((ull)wq << 17) | (ull)(unsigned)s;
            }
            // mo entry: task = N_NODES + s, payload = d
            {
                int task = N_NODES + s, b = task >> BSH;
                int l = atomicAdd(&histB[b], 1);
                image[scB[b] + l] = ((ull)task << 32) | ((ull)wq << 17) | (ull)(unsigned)d;
            }
        }
    }
    __syncthreads();

    // write-out: consecutive LDS positions -> consecutive global addresses
    int nE = 2 * ebn;
    for (int p = t; p < nE; p += 256) {
        ull en = image[p];
        int task = (int)(en >> 32);
        int b = task >> BSH;
        stg[(size_t)gbaseB[b] + (p - scB[b])] = en;
    }
}

// ---------------------------------------------------------------------------
// scatpass: per bucket, load staged entries coalesced, scatter to final
// per-task CSR order in LDS, write plist range out coalesced.
// ---------------------------------------------------------------------------
__global__ __launch_bounds__(256, 2) void scatpass(
    const ull* __restrict__ stg, const int* __restrict__ off,
    unsigned* __restrict__ plist) {
    __shared__ unsigned img[SCAP];             // 24 KB
    __shared__ int toff[257];
    __shared__ int tcnt[256];

    int t = threadIdx.x;
    int b = blockIdx.x;
    int t0 = b << BSH;
    int tl = TASKS - t0;
    if (tl > 256) tl = 256;
    int s0 = off[t0];
    int s1 = off[t0 + tl];
    int n = s1 - s0;

    if (t <= tl) toff[t] = off[t0 + t];
    tcnt[t] = 0;
    __syncthreads();

    if (n <= SCAP) {
        for (int p = t; p < n; p += 256) {
            ull en = stg[(size_t)s0 + p];
            int task = (int)(en >> 32);
            int lt = task - t0;
            int l = atomicAdd(&tcnt[lt], 1);
            img[toff[lt] + l - s0] = (unsigned)(en & 0xFFFFFFFFull);
        }
        __syncthreads();
        for (int p = t; p < n; p += 256)
            plist[s0 + p] = img[p];
    } else {
        // statistically unreachable fallback (bucket > SCAP entries):
        // direct (uncoalesced) global scatter, still correct.
        for (int p = t; p < n; p += 256) {
            ull en = stg[(size_t)s0 + p];
            int task = (int)(en >> 32);
            int lt = task - t0;
            int l = atomicAdd(&tcnt[lt], 1);
            plist[toff[lt] + l] = (unsigned)(en & 0xFFFFFFFFull);
        }
    }
}

// ---------------------------------------------------------------------------
// Weight transpose + hi/lo bf16 split (Wt[n][k] layout).
// ---------------------------------------------------------------------------
__global__ void wsplit0(const float* __restrict__ W0, ushort_t* __restrict__ hi,
                        ushort_t* __restrict__ lo) {
    int id = blockIdx.x * 256 + threadIdx.x;     // 128*384
    if (id >= 128 * K0) return;
    int n = id / K0, k = id % K0;
    float a = W0[k * 128 + n];
    ushort_t h = f2bf(a);
    hi[id] = h;
    lo[id] = f2bf(a - bf2f(h));
}

__global__ void wsplitL(const float* __restrict__ W, ushort_t* __restrict__ hi,
                        ushort_t* __restrict__ lo) {
    int id = blockIdx.x * 256 + threadIdx.x;     // 3*128*128
    if (id >= 3 * 128 * KL) return;
    int l = id / (128 * KL), r = id % (128 * KL);
    int n = r / KL, k = r % KL;
    float a = W[l * 128 * KL + k * 128 + n];
    ushort_t h = f2bf(a);
    hi[id] = h;
    lo[id] = f2bf(a - bf2f(h));
}

// ---------------------------------------------------------------------------
// FUSED gather + layer0. R7: two-task interleave in the gather phase.
// A wave processes task pair (k, k+4) concurrently: both plist loads issue
// together and the inner loop issues 8 xh loads (4+4) back-to-back, so one
// task's reduce/convert bubble overlaps the other's loads (2x memory-level
// parallelism per wave — the R6-identified limiter).
// ---------------------------------------------------------------------------
__global__ __launch_bounds__(256, 6) void layer0_fused(
    const _Float16* __restrict__ xh, const int* __restrict__ off,
    const unsigned* __restrict__ plist, const float* __restrict__ x,
    const ushort_t* __restrict__ Bh, const ushort_t* __restrict__ Bl,
    const float* __restrict__ b0, const float* __restrict__ g0,
    const float* __restrict__ be0, float* __restrict__ h) {
    __shared__ __align__(16) char smem[2 * 16 * PAD0 * 2];   // 25088 B total
    ushort_t* Ahi = (ushort_t*)smem;
    ushort_t* Alo = Ahi + 16 * PAD0;
    float* sout = (float*)smem;                        // aliases Ahi (8448 B)
    float* red  = (float*)(smem + 16 * PAD0 * 2);      // aliases Alo (2048 B)
    float* smv  = red + 16 * 16 * 2;                   // aliases Alo (+128 B)

    int t = threadIdx.x;
    int node0 = blockIdx.x * 16;
    int lane = t & 63, wv = t >> 6;
    int g = lane >> 4, i15 = lane & 15;
    const float wsc = 1.0f / 32768.0f;

    // stage x section (cols 256..383): 16 rows x 32 float4
#pragma unroll
    for (int it = 0; it < 2; ++it) {
        int id = it * 256 + t;
        int r = id >> 5;
        int c = 256 + (id & 31) * 4;
        float4 v = *(const float4*)&x[(size_t)(node0 + r) * D + (c - 256)];
        ushort_t h0 = f2bf(v.x), h1 = f2bf(v.y), h2 = f2bf(v.z), h3 = f2bf(v.w);
        ushort_t l0 = f2bf(v.x - bf2f(h0)), l1 = f2bf(v.y - bf2f(h1));
        ushort_t l2 = f2bf(v.z - bf2f(h2)), l3 = f2bf(v.w - bf2f(h3));
        *(ull*)&Ahi[r * PAD0 + c] = (ull)h0 | ((ull)h1 << 16) | ((ull)h2 << 32) | ((ull)h3 << 48);
        *(ull*)&Alo[r * PAD0 + c] = (ull)l0 | ((ull)l1 << 16) | ((ull)l2 << 32) | ((ull)l3 << 48);
    }

    // gather phase: 32 tasks (16 mi + 16 mo); wave handles pairs (k, k+4)
    for (int pair = 0; pair < 4; ++pair) {
        int kA = wv * 8 + pair;
        int kB = kA + 4;
        int rowA = kA & 15, rowB = kB & 15;
        int cbA = (kA < 16) ? 0 : 128;
        int cbB = (kB < 16) ? 0 : 128;
        int taskA = (kA < 16) ? (node0 + kA) : (N_NODES + node0 + (kA - 16));
        int taskB = (kB < 16) ? (node0 + kB) : (N_NODES + node0 + (kB - 16));
        int e0A = off[taskA], e1A = off[taskA + 1];
        int e0B = off[taskB], e1B = off[taskB + 1];

        float accA[8], accB[8];
#pragma unroll
        for (int r = 0; r < 8; ++r) { accA[r] = 0.f; accB[r] = 0.f; }

        int baseA = e0A, baseB = e0B;
        while (baseA < e1A || baseB < e1B) {
            unsigned pvA = 0, pvB = 0;
            int idxA = baseA + lane, idxB = baseB + lane;
            if (baseA < e1A && idxA < e1A) pvA = plist[idxA];
            if (baseB < e1B && idxB < e1B) pvB = plist[idxB];
            int cntA = (baseA < e1A) ? (e1A - baseA) : 0;
            int cntB = (baseB < e1B) ? (e1B - baseB) : 0;
            if (cntA > 64) cntA = 64;
            if (cntB > 64) cntB = 64;
            int jnA = (cntA + 3) >> 2, jnB = (cntB + 3) >> 2;
            int jA = 0, jB = 0;
            // paired main loop: 8 loads in flight (4 per task)
            for (; jA + 3 < jnA && jB + 3 < jnB; jA += 4, jB += 4) {
                unsigned pA0 = (unsigned)__shfl((int)pvA, (jA + 0) * 4 + g);
                unsigned pA1 = (unsigned)__shfl((int)pvA, (jA + 1) * 4 + g);
                unsigned pA2 = (unsigned)__shfl((int)pvA, (jA + 2) * 4 + g);
                unsigned pA3 = (unsigned)__shfl((int)pvA, (jA + 3) * 4 + g);
                unsigned pB0 = (unsigned)__shfl((int)pvB, (jB + 0) * 4 + g);
                unsigned pB1 = (unsigned)__shfl((int)pvB, (jB + 1) * 4 + g);
                unsigned pB2 = (unsigned)__shfl((int)pvB, (jB + 2) * 4 + g);
                unsigned pB3 = (unsigned)__shfl((int)pvB, (jB + 3) * 4 + g);
                half8 vA0 = *(const half8*)(xh + (size_t)(pA0 & 0x1FFFF) * D + i15 * 8);
                half8 vA1 = *(const half8*)(xh + (size_t)(pA1 & 0x1FFFF) * D + i15 * 8);
                half8 vA2 = *(const half8*)(xh + (size_t)(pA2 & 0x1FFFF) * D + i15 * 8);
                half8 vA3 = *(const half8*)(xh + (size_t)(pA3 & 0x1FFFF) * D + i15 * 8);
                half8 vB0 = *(const half8*)(xh + (size_t)(pB0 & 0x1FFFF) * D + i15 * 8);
                half8 vB1 = *(const half8*)(xh + (size_t)(pB1 & 0x1FFFF) * D + i15 * 8);
                half8 vB2 = *(const half8*)(xh + (size_t)(pB2 & 0x1FFFF) * D + i15 * 8);
                half8 vB3 = *(const half8*)(xh + (size_t)(pB3 & 0x1FFFF) * D + i15 * 8);
                float wA0 = (float)(pA0 >> 17) * wsc;
                float wA1 = (float)(pA1 >> 17) * wsc;
                float wA2 = (float)(pA2 >> 17) * wsc;
                float wA3 = (float)(pA3 >> 17) * wsc;
                float wB0 = (float)(pB0 >> 17) * wsc;
                float wB1 = (float)(pB1 >> 17) * wsc;
                float wB2 = (float)(pB2 >> 17) * wsc;
                float wB3 = (float)(pB3 >> 17) * wsc;
#pragma unroll
                for (int r = 0; r < 8; ++r) accA[r] = fmaf(wA0, (float)vA0[r], accA[r]);
#pragma unroll
                for (int r = 0; r < 8; ++r) accA[r] = fmaf(wA1, (float)vA1[r], accA[r]);
#pragma unroll
                for (int r = 0; r < 8; ++r) accA[r] = fmaf(wA2, (float)vA2[r], accA[r]);
#pragma unroll
                for (int r = 0; r < 8; ++r) accA[r] = fmaf(wA3, (float)vA3[r], accA[r]);
#pragma unroll
                for (int r = 0; r < 8; ++r) accB[r] = fmaf(wB0, (float)vB0[r], accB[r]);
#pragma unroll
                for (int r = 0; r < 8; ++r) accB[r] = fmaf(wB1, (float)vB1[r], accB[r]);
#pragma unroll
                for (int r = 0; r < 8; ++r) accB[r] = fmaf(wB2, (float)vB2[r], accB[r]);
#pragma unroll
                for (int r = 0; r < 8; ++r) accB[r] = fmaf(wB3, (float)vB3[r], accB[r]);
            }
            // A-only unrolled remainder
            for (; jA + 3 < jnA; jA += 4) {
                unsigned p0 = (unsigned)__shfl((int)pvA, (jA + 0) * 4 + g);
                unsigned p1 = (unsigned)__shfl((int)pvA, (jA + 1) * 4 + g);
                unsigned p2 = (unsigned)__shfl((int)pvA, (jA + 2) * 4 + g);
                unsigned p3 = (unsigned)__shfl((int)pvA, (jA + 3) * 4 + g);
                half8 v0 = *(const half8*)(xh + (size_t)(p0 & 0x1FFFF) * D + i15 * 8);
                half8 v1 = *(const half8*)(xh + (size_t)(p1 & 0x1FFFF) * D + i15 * 8);
                half8 v2 = *(const half8*)(xh + (size_t)(p2 & 0x1FFFF) * D + i15 * 8);
                half8 v3 = *(const half8*)(xh + (size_t)(p3 & 0x1FFFF) * D + i15 * 8);
                float w0 = (float)(p0 >> 17) * wsc;
                float w1 = (float)(p1 >> 17) * wsc;
                float w2 = (float)(p2 >> 17) * wsc;
                float w3 = (float)(p3 >> 17) * wsc;
#pragma unroll
                for (int r = 0; r < 8; ++r) accA[r] = fmaf(w0, (float)v0[r], accA[r]);
#pragma unroll
                for (int r = 0; r < 8; ++r) accA[r] = fmaf(w1, (float)v1[r], accA[r]);
#pragma unroll
                for (int r = 0; r < 8; ++r) accA[r] = fmaf(w2, (float)v2[r], accA[r]);
#pragma unroll
                for (int r = 0; r < 8; ++r) accA[r] = fmaf(w3, (float)v3[r], accA[r]);
            }
            // B-only unrolled remainder
            for (; jB + 3 < jnB; jB += 4) {
                unsigned p0 = (unsigned)__shfl((int)pvB, (jB + 0) * 4 + g);
                unsigned p1 = (unsigned)__shfl((int)pvB, (jB + 1) * 4 + g);
                unsigned p2 = (unsigned)__shfl((int)pvB, (jB + 2) * 4 + g);
                unsigned p3 = (unsigned)__shfl((int)pvB, (jB + 3) * 4 + g);
                half8 v0 = *(const half8*)(xh + (size_t)(p0 & 0x1FFFF) * D + i15 * 8);
                half8 v1 = *(const half8*)(xh + (size_t)(p1 & 0x1FFFF) * D + i15 * 8);
                half8 v2 = *(const half8*)(xh + (size_t)(p2 & 0x1FFFF) * D + i15 * 8);
                half8 v3 = *(const half8*)(xh + (size_t)(p3 & 0x1FFFF) * D + i15 * 8);
                float w0 = (float)(p0 >> 17) * wsc;
                float w1 = (float)(p1 >> 17) * wsc;
                float w2 = (float)(p2 >> 17) * wsc;
                float w3 = (float)(p3 >> 17) * wsc;
#pragma unroll
                for (int r = 0; r < 8; ++r) accB[r] = fmaf(w0, (float)v0[r], accB[r]);
#pragma unroll
                for (int r = 0; r < 8; ++r) accB[r] = fmaf(w1, (float)v1[r], accB[r]);
#pragma unroll
                for (int r = 0; r < 8; ++r) accB[r] = fmaf(w2, (float)v2[r], accB[r]);
#pragma unroll
                for (int r = 0; r < 8; ++r) accB[r] = fmaf(w3, (float)v3[r], accB[r]);
            }
            // scalar tails
            for (; jA < jnA; ++jA) {
                unsigned p0 = (unsigned)__shfl((int)pvA, jA * 4 + g);
                half8 v0 = *(const half8*)(xh + (size_t)(p0 & 0x1FFFF) * D + i15 * 8);
                float w0 = (float)(p0 >> 17) * wsc;
#pragma unroll
                for (int r = 0; r < 8; ++r) accA[r] = fmaf(w0, (float)v0[r], accA[r]);
            }
            for (; jB < jnB; ++jB) {
                unsigned p0 = (unsigned)__shfl((int)pvB, jB * 4 + g);
                half8 v0 = *(const half8*)(xh + (size_t)(p0 & 0x1FFFF) * D + i15 * 8);
                float w0 = (float)(p0 >> 17) * wsc;
#pragma unroll
                for (int r = 0; r < 8; ++r) accB[r] = fmaf(w0, (float)v0[r], accB[r]);
            }
            baseA += 64;
            baseB += 64;
        }

#pragma unroll
        for (int r = 0; r < 8; ++r) {
            accA[r] += __shfl_xor(accA[r], 32);
            accA[r] += __shfl_xor(accA[r], 16);
            accB[r] += __shfl_xor(accB[r], 32);
            accB[r] += __shfl_xor(accB[r], 16);
        }
        if (g == 0) {
            ushort_t hh[8], ll[8];
#pragma unroll
            for (int r = 0; r < 8; ++r) {
                hh[r] = f2bf(accA[r]);
                ll[r] = f2bf(accA[r] - bf2f(hh[r]));
            }
            int cc = cbA + i15 * 8;
            *(ull*)&Ahi[rowA * PAD0 + cc] =
                (ull)hh[0] | ((ull)hh[1] << 16) | ((ull)hh[2] << 32) | ((ull)hh[3] << 48);
            *(ull*)&Ahi[rowA * PAD0 + cc + 4] =
                (ull)hh[4] | ((ull)hh[5] << 16) | ((ull)hh[6] << 32) | ((ull)hh[7] << 48);
            *(ull*)&Alo[rowA * PAD0 + cc] =
                (ull)ll[0] | ((ull)ll[1] << 16) | ((ull)ll[2] << 32) | ((ull)ll[3] << 48);
            *(ull*)&Alo[rowA * PAD0 + cc + 4] =
                (ull)ll[4] | ((ull)ll[5] << 16) | ((ull)ll[6] << 32) | ((ull)ll[7] << 48);
#pragma unroll
            for (int r = 0; r < 8; ++r) {
                hh[r] = f2bf(accB[r]);
                ll[r] = f2bf(accB[r] - bf2f(hh[r]));
            }
            cc = cbB + i15 * 8;
            *(ull*)&Ahi[rowB * PAD0 + cc] =
                (ull)hh[0] | ((ull)hh[1] << 16) | ((ull)hh[2] << 32) | ((ull)hh[3] << 48);
            *(ull*)&Ahi[rowB * PAD0 + cc + 4] =
                (ull)hh[4] | ((ull)hh[5] << 16) | ((ull)hh[6] << 32) | ((ull)hh[7] << 48);
            *(ull*)&Alo[rowB * PAD0 + cc] =
                (ull)ll[0] | ((ull)ll[1] << 16) | ((ull)ll[2] << 32) | ((ull)ll[3] << 48);
            *(ull*)&Alo[rowB * PAD0 + cc + 4] =
                (ull)ll[4] | ((ull)ll[5] << 16) | ((ull)ll[6] << 32) | ((ull)ll[7] << 48);
        }
    }
    __syncthreads();

    // MFMA phase: M=16, N=128 (4 waves x 32 cols), K=384
    int quad = lane >> 4, m15 = lane & 15;
    int cw = wv * 32;

    f32x4 acc2[2];
    acc2[0] = (f32x4)0.f;
    acc2[1] = (f32x4)0.f;

    for (int k0 = 0; k0 < K0; k0 += 32) {
        int ka = k0 + quad * 8;
        short8 ah = *(const short8*)&Ahi[m15 * PAD0 + ka];
        short8 al = *(const short8*)&Alo[m15 * PAD0 + ka];
        short8 bh0 = *(const short8*)(Bh + (size_t)(cw + m15) * K0 + ka);
        short8 bh1 = *(const short8*)(Bh + (size_t)(cw + 16 + m15) * K0 + ka);
        short8 bl0 = *(const short8*)(Bl + (size_t)(cw + m15) * K0 + ka);
        short8 bl1 = *(const short8*)(Bl + (size_t)(cw + 16 + m15) * K0 + ka);
        acc2[0] = __builtin_amdgcn_mfma_f32_16x16x32_bf16(ah, bh0, acc2[0], 0, 0, 0);
        acc2[1] = __builtin_amdgcn_mfma_f32_16x16x32_bf16(ah, bh1, acc2[1], 0, 0, 0);
        acc2[0] = __builtin_amdgcn_mfma_f32_16x16x32_bf16(al, bh0, acc2[0], 0, 0, 0);
        acc2[1] = __builtin_amdgcn_mfma_f32_16x16x32_bf16(al, bh1, acc2[1], 0, 0, 0);
        acc2[0] = __builtin_amdgcn_mfma_f32_16x16x32_bf16(ah, bl0, acc2[0], 0, 0, 0);
        acc2[1] = __builtin_amdgcn_mfma_f32_16x16x32_bf16(ah, bl1, acc2[1], 0, 0, 0);
    }
    __syncthreads();

    float bc0 = b0[cw + m15], bc1 = b0[cw + 16 + m15];
#pragma unroll
    for (int ct = 0; ct < 2; ++ct) {
        float bc = ct ? bc1 : bc0;
        int col = cw + ct * 16 + m15;
#pragma unroll
        for (int reg = 0; reg < 4; ++reg) {
            int row = quad * 4 + reg;
            sout[row * SSTR + col] = acc2[ct][reg] + bc;
        }
    }
    __syncthreads();

    {
        int r = t >> 4, p = t & 15;
        float s = 0.f, s2 = 0.f;
        for (int c = p * 8; c < p * 8 + 8; ++c) {
            float v = sout[r * SSTR + c];
            s += v; s2 += v * v;
        }
        red[(r * 16 + p) * 2 + 0] = s;
        red[(r * 16 + p) * 2 + 1] = s2;
    }
    __syncthreads();
    if (t < 16) {
        float ss = 0.f, ss2 = 0.f;
#pragma unroll
        for (int q = 0; q < 16; ++q) {
            ss += red[(t * 16 + q) * 2 + 0];
            ss2 += red[(t * 16 + q) * 2 + 1];
        }
        float m = ss * (1.0f / D);
        float var = ss2 * (1.0f / D) - m * m;
        smv[t * 2 + 0] = m;
        smv[t * 2 + 1] = rsqrtf(var + EPS);
    }
    __syncthreads();

#pragma unroll
    for (int pass = 0; pass < 2; ++pass) {
        int id = pass * 256 + t;
        int r = id >> 5;
        int c = (id & 31) * 4;
        float mm = smv[r * 2 + 0], rs = smv[r * 2 + 1];
        float4 sv = *(const float4*)&sout[r * SSTR + c];
        float4 gv = *(const float4*)&g0[c];
        float4 bv = *(const float4*)&be0[c];
        float4 o;
        o.x = tanh_fast((sv.x - mm) * rs * gv.x + bv.x);
        o.y = tanh_fast((sv.y - mm) * rs * gv.y + bv.y);
        o.z = tanh_fast((sv.z - mm) * rs * gv.z + bv.z);
        o.w = tanh_fast((sv.w - mm) * rs * gv.w + bv.w);
        *(float4*)&h[(size_t)(node0 + r) * D + c] = o;
    }
}

// ---------------------------------------------------------------------------
// FUSED layers 1..3: h = tanh(LN(h @ W_l + b_l)) applied 3x entirely in LDS.
// ---------------------------------------------------------------------------
__global__ __launch_bounds__(256, 4) void layers123(
    const float* hin,
    const ushort_t* __restrict__ Bh, const ushort_t* __restrict__ Bl,
    const float* __restrict__ b, const float* __restrict__ g,
    const float* __restrict__ be, float* hout) {
    __shared__ __align__(16) ushort_t Ahi[32 * PADL];
    __shared__ __align__(16) ushort_t Alo[32 * PADL];
    __shared__ __align__(16) float sout[32 * SSTR];
    __shared__ float red[32][8][2];
    __shared__ float smv[32][2];

    int t = threadIdx.x;
    int node0 = blockIdx.x * 32;

    // stage h -> A-tile (bf16 hi/lo)
#pragma unroll
    for (int i = 0; i < 4; ++i) {
        int id = i * 256 + t;
        int r = id >> 5;
        int c = (id & 31) * 4;
        float4 v = *(const float4*)&hin[(size_t)(node0 + r) * D + c];
        ushort_t h0 = f2bf(v.x), h1 = f2bf(v.y), h2 = f2bf(v.z), h3 = f2bf(v.w);
        ushort_t l0 = f2bf(v.x - bf2f(h0)), l1 = f2bf(v.y - bf2f(h1));
        ushort_t l2 = f2bf(v.z - bf2f(h2)), l3 = f2bf(v.w - bf2f(h3));
        *(ull*)&Ahi[r * PADL + c] = (ull)h0 | ((ull)h1 << 16) | ((ull)h2 << 32) | ((ull)h3 << 48);
        *(ull*)&Alo[r * PADL + c] = (ull)l0 | ((ull)l1 << 16) | ((ull)l2 << 32) | ((ull)l3 << 48);
    }

    int lane = t & 63, wv = t >> 6;
    int quad = lane >> 4, m15 = lane & 15;
    int cw = wv * 32;

    for (int l = 0; l < 3; ++l) {
        const ushort_t* Bhl = Bh + (size_t)l * 128 * KL;
        const ushort_t* Bll = Bl + (size_t)l * 128 * KL;
        __syncthreads();   // A-tile ready (staging or previous write-back)

        f32x4 acc[2][2];
#pragma unroll
        for (int rt = 0; rt < 2; ++rt)
#pragma unroll
            for (int ct = 0; ct < 2; ++ct) acc[rt][ct] = (f32x4)0.f;

#pragma unroll
        for (int k0 = 0; k0 < KL; k0 += 32) {
            int ka = k0 + quad * 8;
            short8 ah0 = *(const short8*)&Ahi[(m15) * PADL + ka];
            short8 ah1 = *(const short8*)&Ahi[(16 + m15) * PADL + ka];
            short8 al0 = *(const short8*)&Alo[(m15) * PADL + ka];
            short8 al1 = *(const short8*)&Alo[(16 + m15) * PADL + ka];
            short8 bh0 = *(const short8*)(Bhl + (size_t)(cw + m15) * KL + ka);
            short8 bh1 = *(const short8*)(Bhl + (size_t)(cw + 16 + m15) * KL + ka);
            short8 bl0 = *(const short8*)(Bll + (size_t)(cw + m15) * KL + ka);
            short8 bl1 = *(const short8*)(Bll + (size_t)(cw + 16 + m15) * KL + ka);
            acc[0][0] = __builtin_amdgcn_mfma_f32_16x16x32_bf16(ah0, bh0, acc[0][0], 0, 0, 0);
            acc[0][1] = __builtin_amdgcn_mfma_f32_16x16x32_bf16(ah0, bh1, acc[0][1], 0, 0, 0);
            acc[1][0] = __builtin_amdgcn_mfma_f32_16x16x32_bf16(ah1, bh0, acc[1][0], 0, 0, 0);
            acc[1][1] = __builtin_amdgcn_mfma_f32_16x16x32_bf16(ah1, bh1, acc[1][1], 0, 0, 0);
            acc[0][0] = __builtin_amdgcn_mfma_f32_16x16x32_bf16(al0, bh0, acc[0][0], 0, 0, 0);
            acc[0][1] = __builtin_amdgcn_mfma_f32_16x16x32_bf16(al0, bh1, acc[0][1], 0, 0, 0);
            acc[1][0] = __builtin_amdgcn_mfma_f32_16x16x32_bf16(al1, bh0, acc[1][0], 0, 0, 0);
            acc[1][1] = __builtin_amdgcn_mfma_f32_16x16x32_bf16(al1, bh1, acc[1][1], 0, 0, 0);
            acc[0][0] = __builtin_amdgcn_mfma_f32_16x16x32_bf16(ah0, bl0, acc[0][0], 0, 0, 0);
            acc[0][1] = __builtin_amdgcn_mfma_f32_16x16x32_bf16(ah0, bl1, acc[0][1], 0, 0, 0);
            acc[1][0] = __builtin_amdgcn_mfma_f32_16x16x32_bf16(ah1, bl0, acc[1][0], 0, 0, 0);
            acc[1][1] = __builtin_amdgcn_mfma_f32_16x16x32_bf16(ah1, bl1, acc[1][1], 0, 0, 0);
        }

        float bc0 = b[l * D + cw + m15], bc1 = b[l * D + cw + 16 + m15];
#pragma unroll
        for (int rt = 0; rt < 2; ++rt)
#pragma unroll
            for (int ct = 0; ct < 2; ++ct) {
                float bc = ct ? bc1 : bc0;
                int col = cw + ct * 16 + m15;
#pragma unroll
                for (int reg = 0; reg < 4; ++reg) {
                    int row = rt * 16 + quad * 4 + reg;
                    sout[row * SSTR + col] = acc[rt][ct][reg] + bc;
                }
            }
        __syncthreads();

        {
            int r = t >> 3, p = t & 7;
            float s = 0.f, s2 = 0.f;
            for (int c = p * 16; c < p * 16 + 16; ++c) {
                float v = sout[r * SSTR + c];
                s += v; s2 += v * v;
            }
            red[r][p][0] = s; red[r][p][1] = s2;
        }
        __syncthreads();
        if (t < 32) {
            float ss = 0.f, ss2 = 0.f;
#pragma unroll
            for (int q = 0; q < 8; ++q) { ss += red[t][q][0]; ss2 += red[t][q][1]; }
            float m = ss * (1.0f / D);
            float var = ss2 * (1.0f / D) - m * m;
            smv[t][0] = m;
            smv[t][1] = rsqrtf(var + EPS);
        }
        __syncthreads();

#pragma unroll
        for (int pass = 0; pass < 4; ++pass) {
            int r = pass * 8 + (t >> 5);
            int c = (t & 31) * 4;
            float mm = smv[r][0], rs = smv[r][1];
            float4 sv = *(const float4*)&sout[r * SSTR + c];
            float4 gv = *(const float4*)&g[l * D + c];
            float4 bv = *(const float4*)&be[l * D + c];
            float o0 = tanh_fast((sv.x - mm) * rs * gv.x + bv.x);
            float o1 = tanh_fast((sv.y - mm) * rs * gv.y + bv.y);
            float o2 = tanh_fast((sv.z - mm) * rs * gv.z + bv.z);
            float o3 = tanh_fast((sv.w - mm) * rs * gv.w + bv.w);
            if (l < 2) {
                ushort_t h0 = f2bf(o0), h1 = f2bf(o1), h2 = f2bf(o2), h3 = f2bf(o3);
                ushort_t l0 = f2bf(o0 - bf2f(h0)), l1 = f2bf(o1 - bf2f(h1));
                ushort_t l2 = f2bf(o2 - bf2f(h2)), l3 = f2bf(o3 - bf2f(h3));
                *(ull*)&Ahi[r * PADL + c] = (ull)h0 | ((ull)h1 << 16) | ((ull)h2 << 32) | ((ull)h3 << 48);
                *(ull*)&Alo[r * PADL + c] = (ull)l0 | ((ull)l1 << 16) | ((ull)l2 << 32) | ((ull)l3 << 48);
            } else {
                *(float4*)&hout[(size_t)(node0 + r) * D + c] =
                    make_float4(o0, o1, o2, o3);
            }
        }
    }
}

static inline char* align64(char* p) {
    return (char*)(((uintptr_t)p + 63) & ~(uintptr_t)63);
}

extern "C" void kernel_launch(void* const* d_in, const int* in_sizes, int n_in,
                              void* d_out, int out_size, void* d_ws, size_t ws_size,
                              hipStream_t stream) {
    const float* x   = (const float*)d_in[0];
    const float* e   = (const float*)d_in[1];
    const int*   ei  = (const int*)d_in[2];
    const float* W0  = (const float*)d_in[3];
    const float* b0  = (const float*)d_in[4];
    const float* g0  = (const float*)d_in[5];
    const float* be0 = (const float*)d_in[6];
    const float* W   = (const float*)d_in[7];
    const float* b   = (const float*)d_in[8];
    const float* g   = (const float*)d_in[9];
    const float* be  = (const float*)d_in[10];
    float* out = (float*)d_out;

    const int* sv = ei;              // edge_index[0] = start
    const int* dv = ei + N_EDGES;    // edge_index[1] = end

    // workspace. stg (25.6 MB, 8B staged entries); W-split buffers alias the
    // cnt region (cnt dead after scan_a).
    char* p = (char*)d_ws;
    char* cnt_base = p;
    int* cnt = (int*)p;           p = align64(p + (size_t)NCNT * 4);          // 0.8 MB
    int* off = (int*)p;           p = align64(p + (size_t)OFF_PAD * 4);       // 0.8 MB
    int* aux = (int*)p;           p = align64(p + 256 * 4);
    unsigned* plist = (unsigned*)p; p = align64(p + (size_t)2 * N_EDGES * 4); // 12.8 MB
    ull* stg = (ull*)p;           p = align64(p + (size_t)2 * N_EDGES * 8);   // 25.6 MB
    _Float16* xh = (_Float16*)p;  p = align64(p + (size_t)N_NODES * D * 2);   // 25.6 MB
    int* bcur = (int*)p;          p = align64(p + (size_t)NB * 4);            // 3.2 KB
    // aliased into cnt region (total 384 KB < 800 KB):
    char* q = cnt_base;
    ushort_t* w0h = (ushort_t*)q;  q = align64(q + (size_t)128 * K0 * 2);
    ushort_t* w0l = (ushort_t*)q;  q = align64(q + (size_t)128 * K0 * 2);
    ushort_t* wlh = (ushort_t*)q;  q = align64(q + (size_t)3 * 128 * KL * 2);
    ushort_t* wll = (ushort_t*)q;

    (void)hipMemsetAsync(cnt, 0, NCNT * sizeof(int), stream);

    cvt_x_kernel<<<(N_NODES * D / 4) / 256, 256, 0, stream>>>(x, xh);
    hist_kernel<<<(N_EDGES + 255) / 256, 256, 0, stream>>>(sv, dv, cnt);
    scan_a<<<SCAN_BLOCKS, 256, 0, stream>>>(cnt, off, aux);
    scan_b<<<1, 256, 0, stream>>>(aux);
    scan_c<<<SCAN_BLOCKS, 256, 0, stream>>>(off, aux);
    binit<<<(NB + 255) / 256, 256, 0, stream>>>(off, bcur);

    // cnt is dead now; its region becomes the W-split buffers.
    wsplit0<<<(128 * K0 + 255) / 256, 256, 0, stream>>>(W0, w0h, w0l);
    wsplitL<<<(3 * 128 * KL + 255) / 256, 256, 0, stream>>>(W, wlh, wll);

    binpass<<<NBB, 256, 0, stream>>>(sv, dv, e, bcur, stg);
    scatpass<<<NB, 256, 0, stream>>>(stg, off, plist);

    layer0_fused<<<N_NODES / 16, 256, 0, stream>>>(xh, off, plist, x,
                                                   w0h, w0l, b0, g0, be0, out);

    layers123<<<N_NODES / 32, 256, 0, stream>>>(out, wlh, wll, b, g, be, out);
}

// Round 8
// 643.803 us; speedup vs baseline: 1.0254x; 1.0254x over previous
//
#include <hip/hip_runtime.h>
#include <math.h>

#define N_NODES 100000
#define N_EDGES 1600000
#define D 128
#define EPS 1e-5f
#define NCNT (2 * N_NODES)
#define SCAN_CHUNK 1024
#define SCAN_BLOCKS ((NCNT + SCAN_CHUNK - 1) / SCAN_CHUNK)   // 196
#define OFF_PAD (SCAN_BLOCKS * SCAN_CHUNK + 1)
#define TASKS (2 * N_NODES)

#define K0 384
#define KL 128
#define PAD0 (K0 + 8)     // bf16 elems per LDS row, layer0
#define PADL (KL + 8)     // bf16 elems per LDS row, layers 1-3
#define SSTR 132          // f32 sout row stride

// --- bucketed fill (multisplit) ---
#define BSH 8                                    // 256 tasks per bucket
#define NB ((TASKS + 255) >> BSH)                // 782 buckets
#define CHUNKE 4096                              // edges per binpass block (round-2 proven)
#define NBB ((N_EDGES + CHUNKE - 1) / CHUNKE)    // 391 blocks
#define SCAP 6144                                // scatpass LDS image capacity

typedef unsigned short ushort_t;
typedef unsigned long long ull;
typedef short short8 __attribute__((ext_vector_type(8)));     // MFMA A/B frag
typedef _Float16 half8 __attribute__((ext_vector_type(8)));   // fp16 x row chunk
typedef _Float16 half4v __attribute__((ext_vector_type(4)));
typedef float f32x4 __attribute__((ext_vector_type(4)));      // MFMA C/D frag

static __device__ __forceinline__ float bf2f(ushort_t u) {
    return __uint_as_float(((unsigned)u) << 16);
}
static __device__ __forceinline__ ushort_t f2bf(float f) {
    unsigned u = __float_as_uint(f);
    u += 0x7FFF + ((u >> 16) & 1);          // RNE
    return (ushort_t)(u >> 16);
}
static __device__ __forceinline__ float tanh_fast(float v) {
    return 1.0f - 2.0f / (__expf(2.0f * v) + 1.0f);
}

// ---------------------------------------------------------------------------
// x (f32) -> xh (fp16), 4 elems/thread.
// ---------------------------------------------------------------------------
__global__ void cvt_x_kernel(const float* __restrict__ x, _Float16* __restrict__ xh) {
    int i = blockIdx.x * blockDim.x + threadIdx.x;   // 3.2M threads
    float4 v = ((const float4*)x)[i];
    half4v h;
    h[0] = (_Float16)v.x; h[1] = (_Float16)v.y;
    h[2] = (_Float16)v.z; h[3] = (_Float16)v.w;
    ((half4v*)xh)[i] = h;
}

// ---------------------------------------------------------------------------
// CSR build: histogram + scan
// ---------------------------------------------------------------------------
__global__ void hist_kernel(const int* __restrict__ sv, const int* __restrict__ dv,
                            int* __restrict__ cnt) {
    int e = blockIdx.x * blockDim.x + threadIdx.x;
    if (e >= N_EDGES) return;
    atomicAdd(&cnt[dv[e]], 1);
    atomicAdd(&cnt[N_NODES + sv[e]], 1);
}

__global__ void scan_a(const int* __restrict__ cnt, int* __restrict__ off,
                       int* __restrict__ aux) {
    __shared__ int lds[256];
    int tid = threadIdx.x;
    int base = blockIdx.x * SCAN_CHUNK + tid * 4;
    int v0 = (base + 0 < NCNT) ? cnt[base + 0] : 0;
    int v1 = (base + 1 < NCNT) ? cnt[base + 1] : 0;
    int v2 = (base + 2 < NCNT) ? cnt[base + 2] : 0;
    int v3 = (base + 3 < NCNT) ? cnt[base + 3] : 0;
    int tot = v0 + v1 + v2 + v3;
    lds[tid] = tot;
    __syncthreads();
    for (int s = 1; s < 256; s <<= 1) {
        int add = (tid >= s) ? lds[tid - s] : 0;
        __syncthreads();
        lds[tid] += add;
        __syncthreads();
    }
    int excl = lds[tid] - tot;
    off[base + 1] = excl + v0;
    off[base + 2] = excl + v0 + v1;
    off[base + 3] = excl + v0 + v1 + v2;
    off[base + 4] = excl + tot;
    if (tid == 255) aux[blockIdx.x] = lds[255];
}

__global__ void scan_b(int* __restrict__ aux) {
    __shared__ int lds[256];
    int tid = threadIdx.x;
    int v = (tid < SCAN_BLOCKS) ? aux[tid] : 0;
    lds[tid] = v;
    __syncthreads();
    for (int s = 1; s < 256; s <<= 1) {
        int add = (tid >= s) ? lds[tid - s] : 0;
        __syncthreads();
        lds[tid] += add;
        __syncthreads();
    }
    aux[tid] = lds[tid] - v;
}

__global__ void scan_c(int* __restrict__ off, const int* __restrict__ aux) {
    int tid = threadIdx.x;
    int add = aux[blockIdx.x];
    int base = blockIdx.x * SCAN_CHUNK + tid * 4;
    off[base + 1] += add;
    off[base + 2] += add;
    off[base + 3] += add;
    off[base + 4] += add;
    if (blockIdx.x == 0 && tid == 0) off[0] = 0;
}

// bucket cursor init: bcur[b] = off[256*b]
__global__ void binit(const int* __restrict__ off, int* __restrict__ bcur) {
    int b = blockIdx.x * 256 + threadIdx.x;
    if (b < NB) bcur[b] = off[b << BSH];
}

// ---------------------------------------------------------------------------
// binpass (round-2 proven config): bin entries into per-bucket regions of
// stg (8B entries: task<<32 | w15<<17 | other).
// ---------------------------------------------------------------------------
__global__ __launch_bounds__(256, 2) void binpass(
    const int* __restrict__ sv, const int* __restrict__ dv,
    const float* __restrict__ ew, int* __restrict__ bcur,
    ull* __restrict__ stg) {
    __shared__ ull image[2 * CHUNKE];          // 64 KB
    __shared__ int histB[NB];
    __shared__ int scB[NB];
    __shared__ int gbaseB[NB];
    __shared__ int partial[256];

    int t = threadIdx.x;
    int eb0 = blockIdx.x * CHUNKE;
    int ebn = N_EDGES - eb0;
    if (ebn > CHUNKE) ebn = CHUNKE;

    for (int i = t; i < NB; i += 256) histB[i] = 0;
    __syncthreads();

    // pass 1: histogram
#pragma unroll
    for (int i = 0; i < CHUNKE / 256; ++i) {
        int k = i * 256 + t;
        if (k < ebn) {
            int e = eb0 + k;
            int s = sv[e], d = dv[e];
            atomicAdd(&histB[d >> BSH], 1);
            atomicAdd(&histB[(N_NODES + s) >> BSH], 1);
        }
    }
    __syncthreads();

    // block exclusive scan of histB[0..NB) (pad to 1024, 4 elems/thread)
    {
        int i0 = t * 4;
        int v0 = (i0 + 0 < NB) ? histB[i0 + 0] : 0;
        int v1 = (i0 + 1 < NB) ? histB[i0 + 1] : 0;
        int v2 = (i0 + 2 < NB) ? histB[i0 + 2] : 0;
        int v3 = (i0 + 3 < NB) ? histB[i0 + 3] : 0;
        int tot = v0 + v1 + v2 + v3;
        partial[t] = tot;
        __syncthreads();
        for (int s = 1; s < 256; s <<= 1) {
            int add = (t >= s) ? partial[t - s] : 0;
            __syncthreads();
            partial[t] += add;
            __syncthreads();
        }
        int excl = partial[t] - tot;
        if (i0 + 0 < NB) scB[i0 + 0] = excl;
        if (i0 + 1 < NB) scB[i0 + 1] = excl + v0;
        if (i0 + 2 < NB) scB[i0 + 2] = excl + v0 + v1;
        if (i0 + 3 < NB) scB[i0 + 3] = excl + v0 + v1 + v2;
    }
    __syncthreads();

    // reserve global segments; reset histB for reuse as running counters
    for (int i = t; i < NB; i += 256) {
        int n = histB[i];
        gbaseB[i] = (n > 0) ? atomicAdd(&bcur[i], n) : 0;
        histB[i] = 0;
    }
    __syncthreads();

    // pass 2: scatter entries into LDS image in bucket order
#pragma unroll
    for (int i = 0; i < CHUNKE / 256; ++i) {
        int k = i * 256 + t;
        if (k < ebn) {
            int e = eb0 + k;
            int s = sv[e], d = dv[e];
            float w = ew[e];
            unsigned wq = (unsigned)(w * 32768.0f + 0.5f);
            if (wq > 32767u) wq = 32767u;
            // mi entry: task = d, payload = s
            {
                int task = d, b = task >> BSH;
                int l = atomicAdd(&histB[b], 1);
                image[scB[b] + l] = ((ull)task << 32) | ((ull)wq << 17) | (ull)(unsigned)s;
            }
            // mo entry: task = N_NODES + s, payload = d
            {
                int task = N_NODES + s, b = task >> BSH;
                int l = atomicAdd(&histB[b], 1);
                image[scB[b] + l] = ((ull)task << 32) | ((ull)wq << 17) | (ull)(unsigned)d;
            }
        }
    }
    __syncthreads();

    // write-out: consecutive LDS positions -> consecutive global addresses
    int nE = 2 * ebn;
    for (int p = t; p < nE; p += 256) {
        ull en = image[p];
        int task = (int)(en >> 32);
        int b = task >> BSH;
        stg[(size_t)gbaseB[b] + (p - scB[b])] = en;
    }
}

// ---------------------------------------------------------------------------
// scatpass: per bucket, load staged entries coalesced, scatter to final
// per-task CSR order in LDS, write plist range out coalesced.
// ---------------------------------------------------------------------------
__global__ __launch_bounds__(256, 2) void scatpass(
    const ull* __restrict__ stg, const int* __restrict__ off,
    unsigned* __restrict__ plist) {
    __shared__ unsigned img[SCAP];             // 24 KB
    __shared__ int toff[257];
    __shared__ int tcnt[256];

    int t = threadIdx.x;
    int b = blockIdx.x;
    int t0 = b << BSH;
    int tl = TASKS - t0;
    if (tl > 256) tl = 256;
    int s0 = off[t0];
    int s1 = off[t0 + tl];
    int n = s1 - s0;

    if (t <= tl) toff[t] = off[t0 + t];
    tcnt[t] = 0;
    __syncthreads();

    if (n <= SCAP) {
        for (int p = t; p < n; p += 256) {
            ull en = stg[(size_t)s0 + p];
            int task = (int)(en >> 32);
            int lt = task - t0;
            int l = atomicAdd(&tcnt[lt], 1);
            img[toff[lt] + l - s0] = (unsigned)(en & 0xFFFFFFFFull);
        }
        __syncthreads();
        for (int p = t; p < n; p += 256)
            plist[s0 + p] = img[p];
    } else {
        // statistically unreachable fallback (bucket > SCAP entries):
        // direct (uncoalesced) global scatter, still correct.
        for (int p = t; p < n; p += 256) {
            ull en = stg[(size_t)s0 + p];
            int task = (int)(en >> 32);
            int lt = task - t0;
            int l = atomicAdd(&tcnt[lt], 1);
            plist[toff[lt] + l] = (unsigned)(en & 0xFFFFFFFFull);
        }
    }
}

// ---------------------------------------------------------------------------
// Weight transpose + hi/lo bf16 split (Wt[n][k] layout).
// ---------------------------------------------------------------------------
__global__ void wsplit0(const float* __restrict__ W0, ushort_t* __restrict__ hi,
                        ushort_t* __restrict__ lo) {
    int id = blockIdx.x * 256 + threadIdx.x;     // 128*384
    if (id >= 128 * K0) return;
    int n = id / K0, k = id % K0;
    float a = W0[k * 128 + n];
    ushort_t h = f2bf(a);
    hi[id] = h;
    lo[id] = f2bf(a - bf2f(h));
}

__global__ void wsplitL(const float* __restrict__ W, ushort_t* __restrict__ hi,
                        ushort_t* __restrict__ lo) {
    int id = blockIdx.x * 256 + threadIdx.x;     // 3*128*128
    if (id >= 3 * 128 * KL) return;
    int l = id / (128 * KL), r = id % (128 * KL);
    int n = r / KL, k = r % KL;
    float a = W[l * 128 * KL + k * 128 + n];
    ushort_t h = f2bf(a);
    hi[id] = h;
    lo[id] = f2bf(a - bf2f(h));
}

// ---------------------------------------------------------------------------
// FUSED gather + layer0. R8: two-task interleave (R7) + launch_bounds
// (256,4) so the allocator has a 128-VGPR budget — R7's (256,6) pinned it
// at 40 VGPRs and spilled the 8 in-flight half8 loads to scratch
// (+130 MB FETCH/WRITE, net regression). 4 blocks/CU is acceptable:
// R5->R6 showed wave count is not this kernel's limiter; per-wave MLP is.
// ---------------------------------------------------------------------------
__global__ __launch_bounds__(256, 4) void layer0_fused(
    const _Float16* __restrict__ xh, const int* __restrict__ off,
    const unsigned* __restrict__ plist, const float* __restrict__ x,
    const ushort_t* __restrict__ Bh, const ushort_t* __restrict__ Bl,
    const float* __restrict__ b0, const float* __restrict__ g0,
    const float* __restrict__ be0, float* __restrict__ h) {
    __shared__ __align__(16) char smem[2 * 16 * PAD0 * 2];   // 25088 B total
    ushort_t* Ahi = (ushort_t*)smem;
    ushort_t* Alo = Ahi + 16 * PAD0;
    float* sout = (float*)smem;                        // aliases Ahi (8448 B)
    float* red  = (float*)(smem + 16 * PAD0 * 2);      // aliases Alo (2048 B)
    float* smv  = red + 16 * 16 * 2;                   // aliases Alo (+128 B)

    int t = threadIdx.x;
    int node0 = blockIdx.x * 16;
    int lane = t & 63, wv = t >> 6;
    int g = lane >> 4, i15 = lane & 15;
    const float wsc = 1.0f / 32768.0f;

    // stage x section (cols 256..383): 16 rows x 32 float4
#pragma unroll
    for (int it = 0; it < 2; ++it) {
        int id = it * 256 + t;
        int r = id >> 5;
        int c = 256 + (id & 31) * 4;
        float4 v = *(const float4*)&x[(size_t)(node0 + r) * D + (c - 256)];
        ushort_t h0 = f2bf(v.x), h1 = f2bf(v.y), h2 = f2bf(v.z), h3 = f2bf(v.w);
        ushort_t l0 = f2bf(v.x - bf2f(h0)), l1 = f2bf(v.y - bf2f(h1));
        ushort_t l2 = f2bf(v.z - bf2f(h2)), l3 = f2bf(v.w - bf2f(h3));
        *(ull*)&Ahi[r * PAD0 + c] = (ull)h0 | ((ull)h1 << 16) | ((ull)h2 << 32) | ((ull)h3 << 48);
        *(ull*)&Alo[r * PAD0 + c] = (ull)l0 | ((ull)l1 << 16) | ((ull)l2 << 32) | ((ull)l3 << 48);
    }

    // gather phase: 32 tasks (16 mi + 16 mo); wave handles pairs (k, k+4)
    for (int pair = 0; pair < 4; ++pair) {
        int kA = wv * 8 + pair;
        int kB = kA + 4;
        int rowA = kA & 15, rowB = kB & 15;
        int cbA = (kA < 16) ? 0 : 128;
        int cbB = (kB < 16) ? 0 : 128;
        int taskA = (kA < 16) ? (node0 + kA) : (N_NODES + node0 + (kA - 16));
        int taskB = (kB < 16) ? (node0 + kB) : (N_NODES + node0 + (kB - 16));
        int e0A = off[taskA], e1A = off[taskA + 1];
        int e0B = off[taskB], e1B = off[taskB + 1];

        float accA[8], accB[8];
#pragma unroll
        for (int r = 0; r < 8; ++r) { accA[r] = 0.f; accB[r] = 0.f; }

        int baseA = e0A, baseB = e0B;
        while (baseA < e1A || baseB < e1B) {
            unsigned pvA = 0, pvB = 0;
            int idxA = baseA + lane, idxB = baseB + lane;
            if (baseA < e1A && idxA < e1A) pvA = plist[idxA];
            if (baseB < e1B && idxB < e1B) pvB = plist[idxB];
            int cntA = (baseA < e1A) ? (e1A - baseA) : 0;
            int cntB = (baseB < e1B) ? (e1B - baseB) : 0;
            if (cntA > 64) cntA = 64;
            if (cntB > 64) cntB = 64;
            int jnA = (cntA + 3) >> 2, jnB = (cntB + 3) >> 2;
            int jA = 0, jB = 0;
            // paired main loop: 8 loads in flight (4 per task)
            for (; jA + 3 < jnA && jB + 3 < jnB; jA += 4, jB += 4) {
                unsigned pA0 = (unsigned)__shfl((int)pvA, (jA + 0) * 4 + g);
                unsigned pA1 = (unsigned)__shfl((int)pvA, (jA + 1) * 4 + g);
                unsigned pA2 = (unsigned)__shfl((int)pvA, (jA + 2) * 4 + g);
                unsigned pA3 = (unsigned)__shfl((int)pvA, (jA + 3) * 4 + g);
                unsigned pB0 = (unsigned)__shfl((int)pvB, (jB + 0) * 4 + g);
                unsigned pB1 = (unsigned)__shfl((int)pvB, (jB + 1) * 4 + g);
                unsigned pB2 = (unsigned)__shfl((int)pvB, (jB + 2) * 4 + g);
                unsigned pB3 = (unsigned)__shfl((int)pvB, (jB + 3) * 4 + g);
                half8 vA0 = *(const half8*)(xh + (size_t)(pA0 & 0x1FFFF) * D + i15 * 8);
                half8 vA1 = *(const half8*)(xh + (size_t)(pA1 & 0x1FFFF) * D + i15 * 8);
                half8 vA2 = *(const half8*)(xh + (size_t)(pA2 & 0x1FFFF) * D + i15 * 8);
                half8 vA3 = *(const half8*)(xh + (size_t)(pA3 & 0x1FFFF) * D + i15 * 8);
                half8 vB0 = *(const half8*)(xh + (size_t)(pB0 & 0x1FFFF) * D + i15 * 8);
                half8 vB1 = *(const half8*)(xh + (size_t)(pB1 & 0x1FFFF) * D + i15 * 8);
                half8 vB2 = *(const half8*)(xh + (size_t)(pB2 & 0x1FFFF) * D + i15 * 8);
                half8 vB3 = *(const half8*)(xh + (size_t)(pB3 & 0x1FFFF) * D + i15 * 8);
                float wA0 = (float)(pA0 >> 17) * wsc;
                float wA1 = (float)(pA1 >> 17) * wsc;
                float wA2 = (float)(pA2 >> 17) * wsc;
                float wA3 = (float)(pA3 >> 17) * wsc;
                float wB0 = (float)(pB0 >> 17) * wsc;
                float wB1 = (float)(pB1 >> 17) * wsc;
                float wB2 = (float)(pB2 >> 17) * wsc;
                float wB3 = (float)(pB3 >> 17) * wsc;
#pragma unroll
                for (int r = 0; r < 8; ++r) accA[r] = fmaf(wA0, (float)vA0[r], accA[r]);
#pragma unroll
                for (int r = 0; r < 8; ++r) accA[r] = fmaf(wA1, (float)vA1[r], accA[r]);
#pragma unroll
                for (int r = 0; r < 8; ++r) accA[r] = fmaf(wA2, (float)vA2[r], accA[r]);
#pragma unroll
                for (int r = 0; r < 8; ++r) accA[r] = fmaf(wA3, (float)vA3[r], accA[r]);
#pragma unroll
                for (int r = 0; r < 8; ++r) accB[r] = fmaf(wB0, (float)vB0[r], accB[r]);
#pragma unroll
                for (int r = 0; r < 8; ++r) accB[r] = fmaf(wB1, (float)vB1[r], accB[r]);
#pragma unroll
                for (int r = 0; r < 8; ++r) accB[r] = fmaf(wB2, (float)vB2[r], accB[r]);
#pragma unroll
                for (int r = 0; r < 8; ++r) accB[r] = fmaf(wB3, (float)vB3[r], accB[r]);
            }
            // A-only unrolled remainder
            for (; jA + 3 < jnA; jA += 4) {
                unsigned p0 = (unsigned)__shfl((int)pvA, (jA + 0) * 4 + g);
                unsigned p1 = (unsigned)__shfl((int)pvA, (jA + 1) * 4 + g);
                unsigned p2 = (unsigned)__shfl((int)pvA, (jA + 2) * 4 + g);
                unsigned p3 = (unsigned)__shfl((int)pvA, (jA + 3) * 4 + g);
                half8 v0 = *(const half8*)(xh + (size_t)(p0 & 0x1FFFF) * D + i15 * 8);
                half8 v1 = *(const half8*)(xh + (size_t)(p1 & 0x1FFFF) * D + i15 * 8);
                half8 v2 = *(const half8*)(xh + (size_t)(p2 & 0x1FFFF) * D + i15 * 8);
                half8 v3 = *(const half8*)(xh + (size_t)(p3 & 0x1FFFF) * D + i15 * 8);
                float w0 = (float)(p0 >> 17) * wsc;
                float w1 = (float)(p1 >> 17) * wsc;
                float w2 = (float)(p2 >> 17) * wsc;
                float w3 = (float)(p3 >> 17) * wsc;
#pragma unroll
                for (int r = 0; r < 8; ++r) accA[r] = fmaf(w0, (float)v0[r], accA[r]);
#pragma unroll
                for (int r = 0; r < 8; ++r) accA[r] = fmaf(w1, (float)v1[r], accA[r]);
#pragma unroll
                for (int r = 0; r < 8; ++r) accA[r] = fmaf(w2, (float)v2[r], accA[r]);
#pragma unroll
                for (int r = 0; r < 8; ++r) accA[r] = fmaf(w3, (float)v3[r], accA[r]);
            }
            // B-only unrolled remainder
            for (; jB + 3 < jnB; jB += 4) {
                unsigned p0 = (unsigned)__shfl((int)pvB, (jB + 0) * 4 + g);
                unsigned p1 = (unsigned)__shfl((int)pvB, (jB + 1) * 4 + g);
                unsigned p2 = (unsigned)__shfl((int)pvB, (jB + 2) * 4 + g);
                unsigned p3 = (unsigned)__shfl((int)pvB, (jB + 3) * 4 + g);
                half8 v0 = *(const half8*)(xh + (size_t)(p0 & 0x1FFFF) * D + i15 * 8);
                half8 v1 = *(const half8*)(xh + (size_t)(p1 & 0x1FFFF) * D + i15 * 8);
                half8 v2 = *(const half8*)(xh + (size_t)(p2 & 0x1FFFF) * D + i15 * 8);
                half8 v3 = *(const half8*)(xh + (size_t)(p3 & 0x1FFFF) * D + i15 * 8);
                float w0 = (float)(p0 >> 17) * wsc;
                float w1 = (float)(p1 >> 17) * wsc;
                float w2 = (float)(p2 >> 17) * wsc;
                float w3 = (float)(p3 >> 17) * wsc;
#pragma unroll
                for (int r = 0; r < 8; ++r) accB[r] = fmaf(w0, (float)v0[r], accB[r]);
#pragma unroll
                for (int r = 0; r < 8; ++r) accB[r] = fmaf(w1, (float)v1[r], accB[r]);
#pragma unroll
                for (int r = 0; r < 8; ++r) accB[r] = fmaf(w2, (float)v2[r], accB[r]);
#pragma unroll
                for (int r = 0; r < 8; ++r) accB[r] = fmaf(w3, (float)v3[r], accB[r]);
            }
            // scalar tails
            for (; jA < jnA; ++jA) {
                unsigned p0 = (unsigned)__shfl((int)pvA, jA * 4 + g);
                half8 v0 = *(const half8*)(xh + (size_t)(p0 & 0x1FFFF) * D + i15 * 8);
                float w0 = (float)(p0 >> 17) * wsc;
#pragma unroll
                for (int r = 0; r < 8; ++r) accA[r] = fmaf(w0, (float)v0[r], accA[r]);
            }
            for (; jB < jnB; ++jB) {
                unsigned p0 = (unsigned)__shfl((int)pvB, jB * 4 + g);
                half8 v0 = *(const half8*)(xh + (size_t)(p0 & 0x1FFFF) * D + i15 * 8);
                float w0 = (float)(p0 >> 17) * wsc;
#pragma unroll
                for (int r = 0; r < 8; ++r) accB[r] = fmaf(w0, (float)v0[r], accB[r]);
            }
            baseA += 64;
            baseB += 64;
        }

#pragma unroll
        for (int r = 0; r < 8; ++r) {
            accA[r] += __shfl_xor(accA[r], 32);
            accA[r] += __shfl_xor(accA[r], 16);
            accB[r] += __shfl_xor(accB[r], 32);
            accB[r] += __shfl_xor(accB[r], 16);
        }
        if (g == 0) {
            ushort_t hh[8], ll[8];
#pragma unroll
            for (int r = 0; r < 8; ++r) {
                hh[r] = f2bf(accA[r]);
                ll[r] = f2bf(accA[r] - bf2f(hh[r]));
            }
            int cc = cbA + i15 * 8;
            *(ull*)&Ahi[rowA * PAD0 + cc] =
                (ull)hh[0] | ((ull)hh[1] << 16) | ((ull)hh[2] << 32) | ((ull)hh[3] << 48);
            *(ull*)&Ahi[rowA * PAD0 + cc + 4] =
                (ull)hh[4] | ((ull)hh[5] << 16) | ((ull)hh[6] << 32) | ((ull)hh[7] << 48);
            *(ull*)&Alo[rowA * PAD0 + cc] =
                (ull)ll[0] | ((ull)ll[1] << 16) | ((ull)ll[2] << 32) | ((ull)ll[3] << 48);
            *(ull*)&Alo[rowA * PAD0 + cc + 4] =
                (ull)ll[4] | ((ull)ll[5] << 16) | ((ull)ll[6] << 32) | ((ull)ll[7] << 48);
#pragma unroll
            for (int r = 0; r < 8; ++r) {
                hh[r] = f2bf(accB[r]);
                ll[r] = f2bf(accB[r] - bf2f(hh[r]));
            }
            cc = cbB + i15 * 8;
            *(ull*)&Ahi[rowB * PAD0 + cc] =
                (ull)hh[0] | ((ull)hh[1] << 16) | ((ull)hh[2] << 32) | ((ull)hh[3] << 48);
            *(ull*)&Ahi[rowB * PAD0 + cc + 4] =
                (ull)hh[4] | ((ull)hh[5] << 16) | ((ull)hh[6] << 32) | ((ull)hh[7] << 48);
            *(ull*)&Alo[rowB * PAD0 + cc] =
                (ull)ll[0] | ((ull)ll[1] << 16) | ((ull)ll[2] << 32) | ((ull)ll[3] << 48);
            *(ull*)&Alo[rowB * PAD0 + cc + 4] =
                (ull)ll[4] | ((ull)ll[5] << 16) | ((ull)ll[6] << 32) | ((ull)ll[7] << 48);
        }
    }
    __syncthreads();

    // MFMA phase: M=16, N=128 (4 waves x 32 cols), K=384
    int quad = lane >> 4, m15 = lane & 15;
    int cw = wv * 32;

    f32x4 acc2[2];
    acc2[0] = (f32x4)0.f;
    acc2[1] = (f32x4)0.f;

    for (int k0 = 0; k0 < K0; k0 += 32) {
        int ka = k0 + quad * 8;
        short8 ah = *(const short8*)&Ahi[m15 * PAD0 + ka];
        short8 al = *(const short8*)&Alo[m15 * PAD0 + ka];
        short8 bh0 = *(const short8*)(Bh + (size_t)(cw + m15) * K0 + ka);
        short8 bh1 = *(const short8*)(Bh + (size_t)(cw + 16 + m15) * K0 + ka);
        short8 bl0 = *(const short8*)(Bl + (size_t)(cw + m15) * K0 + ka);
        short8 bl1 = *(const short8*)(Bl + (size_t)(cw + 16 + m15) * K0 + ka);
        acc2[0] = __builtin_amdgcn_mfma_f32_16x16x32_bf16(ah, bh0, acc2[0], 0, 0, 0);
        acc2[1] = __builtin_amdgcn_mfma_f32_16x16x32_bf16(ah, bh1, acc2[1], 0, 0, 0);
        acc2[0] = __builtin_amdgcn_mfma_f32_16x16x32_bf16(al, bh0, acc2[0], 0, 0, 0);
        acc2[1] = __builtin_amdgcn_mfma_f32_16x16x32_bf16(al, bh1, acc2[1], 0, 0, 0);
        acc2[0] = __builtin_amdgcn_mfma_f32_16x16x32_bf16(ah, bl0, acc2[0], 0, 0, 0);
        acc2[1] = __builtin_amdgcn_mfma_f32_16x16x32_bf16(ah, bl1, acc2[1], 0, 0, 0);
    }
    __syncthreads();

    float bc0 = b0[cw + m15], bc1 = b0[cw + 16 + m15];
#pragma unroll
    for (int ct = 0; ct < 2; ++ct) {
        float bc = ct ? bc1 : bc0;
        int col = cw + ct * 16 + m15;
#pragma unroll
        for (int reg = 0; reg < 4; ++reg) {
            int row = quad * 4 + reg;
            sout[row * SSTR + col] = acc2[ct][reg] + bc;
        }
    }
    __syncthreads();

    {
        int r = t >> 4, p = t & 15;
        float s = 0.f, s2 = 0.f;
        for (int c = p * 8; c < p * 8 + 8; ++c) {
            float v = sout[r * SSTR + c];
            s += v; s2 += v * v;
        }
        red[(r * 16 + p) * 2 + 0] = s;
        red[(r * 16 + p) * 2 + 1] = s2;
    }
    __syncthreads();
    if (t < 16) {
        float ss = 0.f, ss2 = 0.f;
#pragma unroll
        for (int q = 0; q < 16; ++q) {
            ss += red[(t * 16 + q) * 2 + 0];
            ss2 += red[(t * 16 + q) * 2 + 1];
        }
        float m = ss * (1.0f / D);
        float var = ss2 * (1.0f / D) - m * m;
        smv[t * 2 + 0] = m;
        smv[t * 2 + 1] = rsqrtf(var + EPS);
    }
    __syncthreads();

#pragma unroll
    for (int pass = 0; pass < 2; ++pass) {
        int id = pass * 256 + t;
        int r = id >> 5;
        int c = (id & 31) * 4;
        float mm = smv[r * 2 + 0], rs = smv[r * 2 + 1];
        float4 sv = *(const float4*)&sout[r * SSTR + c];
        float4 gv = *(const float4*)&g0[c];
        float4 bv = *(const float4*)&be0[c];
        float4 o;
        o.x = tanh_fast((sv.x - mm) * rs * gv.x + bv.x);
        o.y = tanh_fast((sv.y - mm) * rs * gv.y + bv.y);
        o.z = tanh_fast((sv.z - mm) * rs * gv.z + bv.z);
        o.w = tanh_fast((sv.w - mm) * rs * gv.w + bv.w);
        *(float4*)&h[(size_t)(node0 + r) * D + c] = o;
    }
}

// ---------------------------------------------------------------------------
// FUSED layers 1..3: h = tanh(LN(h @ W_l + b_l)) applied 3x entirely in LDS.
// ---------------------------------------------------------------------------
__global__ __launch_bounds__(256, 4) void layers123(
    const float* hin,
    const ushort_t* __restrict__ Bh, const ushort_t* __restrict__ Bl,
    const float* __restrict__ b, const float* __restrict__ g,
    const float* __restrict__ be, float* hout) {
    __shared__ __align__(16) ushort_t Ahi[32 * PADL];
    __shared__ __align__(16) ushort_t Alo[32 * PADL];
    __shared__ __align__(16) float sout[32 * SSTR];
    __shared__ float red[32][8][2];
    __shared__ float smv[32][2];

    int t = threadIdx.x;
    int node0 = blockIdx.x * 32;

    // stage h -> A-tile (bf16 hi/lo)
#pragma unroll
    for (int i = 0; i < 4; ++i) {
        int id = i * 256 + t;
        int r = id >> 5;
        int c = (id & 31) * 4;
        float4 v = *(const float4*)&hin[(size_t)(node0 + r) * D + c];
        ushort_t h0 = f2bf(v.x), h1 = f2bf(v.y), h2 = f2bf(v.z), h3 = f2bf(v.w);
        ushort_t l0 = f2bf(v.x - bf2f(h0)), l1 = f2bf(v.y - bf2f(h1));
        ushort_t l2 = f2bf(v.z - bf2f(h2)), l3 = f2bf(v.w - bf2f(h3));
        *(ull*)&Ahi[r * PADL + c] = (ull)h0 | ((ull)h1 << 16) | ((ull)h2 << 32) | ((ull)h3 << 48);
        *(ull*)&Alo[r * PADL + c] = (ull)l0 | ((ull)l1 << 16) | ((ull)l2 << 32) | ((ull)l3 << 48);
    }

    int lane = t & 63, wv = t >> 6;
    int quad = lane >> 4, m15 = lane & 15;
    int cw = wv * 32;

    for (int l = 0; l < 3; ++l) {
        const ushort_t* Bhl = Bh + (size_t)l * 128 * KL;
        const ushort_t* Bll = Bl + (size_t)l * 128 * KL;
        __syncthreads();   // A-tile ready (staging or previous write-back)

        f32x4 acc[2][2];
#pragma unroll
        for (int rt = 0; rt < 2; ++rt)
#pragma unroll
            for (int ct = 0; ct < 2; ++ct) acc[rt][ct] = (f32x4)0.f;

#pragma unroll
        for (int k0 = 0; k0 < KL; k0 += 32) {
            int ka = k0 + quad * 8;
            short8 ah0 = *(const short8*)&Ahi[(m15) * PADL + ka];
            short8 ah1 = *(const short8*)&Ahi[(16 + m15) * PADL + ka];
            short8 al0 = *(const short8*)&Alo[(m15) * PADL + ka];
            short8 al1 = *(const short8*)&Alo[(16 + m15) * PADL + ka];
            short8 bh0 = *(const short8*)(Bhl + (size_t)(cw + m15) * KL + ka);
            short8 bh1 = *(const short8*)(Bhl + (size_t)(cw + 16 + m15) * KL + ka);
            short8 bl0 = *(const short8*)(Bll + (size_t)(cw + m15) * KL + ka);
            short8 bl1 = *(const short8*)(Bll + (size_t)(cw + 16 + m15) * KL + ka);
            acc[0][0] = __builtin_amdgcn_mfma_f32_16x16x32_bf16(ah0, bh0, acc[0][0], 0, 0, 0);
            acc[0][1] = __builtin_amdgcn_mfma_f32_16x16x32_bf16(ah0, bh1, acc[0][1], 0, 0, 0);
            acc[1][0] = __builtin_amdgcn_mfma_f32_16x16x32_bf16(ah1, bh0, acc[1][0], 0, 0, 0);
            acc[1][1] = __builtin_amdgcn_mfma_f32_16x16x32_bf16(ah1, bh1, acc[1][1], 0, 0, 0);
            acc[0][0] = __builtin_amdgcn_mfma_f32_16x16x32_bf16(al0, bh0, acc[0][0], 0, 0, 0);
            acc[0][1] = __builtin_amdgcn_mfma_f32_16x16x32_bf16(al0, bh1, acc[0][1], 0, 0, 0);
            acc[1][0] = __builtin_amdgcn_mfma_f32_16x16x32_bf16(al1, bh0, acc[1][0], 0, 0, 0);
            acc[1][1] = __builtin_amdgcn_mfma_f32_16x16x32_bf16(al1, bh1, acc[1][1], 0, 0, 0);
            acc[0][0] = __builtin_amdgcn_mfma_f32_16x16x32_bf16(ah0, bl0, acc[0][0], 0, 0, 0);
            acc[0][1] = __builtin_amdgcn_mfma_f32_16x16x32_bf16(ah0, bl1, acc[0][1], 0, 0, 0);
            acc[1][0] = __builtin_amdgcn_mfma_f32_16x16x32_bf16(ah1, bl0, acc[1][0], 0, 0, 0);
            acc[1][1] = __builtin_amdgcn_mfma_f32_16x16x32_bf16(ah1, bl1, acc[1][1], 0, 0, 0);
        }

        float bc0 = b[l * D + cw + m15], bc1 = b[l * D + cw + 16 + m15];
#pragma unroll
        for (int rt = 0; rt < 2; ++rt)
#pragma unroll
            for (int ct = 0; ct < 2; ++ct) {
                float bc = ct ? bc1 : bc0;
                int col = cw + ct * 16 + m15;
#pragma unroll
                for (int reg = 0; reg < 4; ++reg) {
                    int row = rt * 16 + quad * 4 + reg;
                    sout[row * SSTR + col] = acc[rt][ct][reg] + bc;
                }
            }
        __syncthreads();

        {
            int r = t >> 3, p = t & 7;
            float s = 0.f, s2 = 0.f;
            for (int c = p * 16; c < p * 16 + 16; ++c) {
                float v = sout[r * SSTR + c];
                s += v; s2 += v * v;
            }
            red[r][p][0] = s; red[r][p][1] = s2;
        }
        __syncthreads();
        if (t < 32) {
            float ss = 0.f, ss2 = 0.f;
#pragma unroll
            for (int q = 0; q < 8; ++q) { ss += red[t][q][0]; ss2 += red[t][q][1]; }
            float m = ss * (1.0f / D);
            float var = ss2 * (1.0f / D) - m * m;
            smv[t][0] = m;
            smv[t][1] = rsqrtf(var + EPS);
        }
        __syncthreads();

#pragma unroll
        for (int pass = 0; pass < 4; ++pass) {
            int r = pass * 8 + (t >> 5);
            int c = (t & 31) * 4;
            float mm = smv[r][0], rs = smv[r][1];
            float4 sv = *(const float4*)&sout[r * SSTR + c];
            float4 gv = *(const float4*)&g[l * D + c];
            float4 bv = *(const float4*)&be[l * D + c];
            float o0 = tanh_fast((sv.x - mm) * rs * gv.x + bv.x);
            float o1 = tanh_fast((sv.y - mm) * rs * gv.y + bv.y);
            float o2 = tanh_fast((sv.z - mm) * rs * gv.z + bv.z);
            float o3 = tanh_fast((sv.w - mm) * rs * gv.w + bv.w);
            if (l < 2) {
                ushort_t h0 = f2bf(o0), h1 = f2bf(o1), h2 = f2bf(o2), h3 = f2bf(o3);
                ushort_t l0 = f2bf(o0 - bf2f(h0)), l1 = f2bf(o1 - bf2f(h1));
                ushort_t l2 = f2bf(o2 - bf2f(h2)), l3 = f2bf(o3 - bf2f(h3));
                *(ull*)&Ahi[r * PADL + c] = (ull)h0 | ((ull)h1 << 16) | ((ull)h2 << 32) | ((ull)h3 << 48);
                *(ull*)&Alo[r * PADL + c] = (ull)l0 | ((ull)l1 << 16) | ((ull)l2 << 32) | ((ull)l3 << 48);
            } else {
                *(float4*)&hout[(size_t)(node0 + r) * D + c] =
                    make_float4(o0, o1, o2, o3);
            }
        }
    }
}

static inline char* align64(char* p) {
    return (char*)(((uintptr_t)p + 63) & ~(uintptr_t)63);
}

extern "C" void kernel_launch(void* const* d_in, const int* in_sizes, int n_in,
                              void* d_out, int out_size, void* d_ws, size_t ws_size,
                              hipStream_t stream) {
    const float* x   = (const float*)d_in[0];
    const float* e   = (const float*)d_in[1];
    const int*   ei  = (const int*)d_in[2];
    const float* W0  = (const float*)d_in[3];
    const float* b0  = (const float*)d_in[4];
    const float* g0  = (const float*)d_in[5];
    const float* be0 = (const float*)d_in[6];
    const float* W   = (const float*)d_in[7];
    const float* b   = (const float*)d_in[8];
    const float* g   = (const float*)d_in[9];
    const float* be  = (const float*)d_in[10];
    float* out = (float*)d_out;

    const int* sv = ei;              // edge_index[0] = start
    const int* dv = ei + N_EDGES;    // edge_index[1] = end

    // workspace. stg (25.6 MB, 8B staged entries); W-split buffers alias the
    // cnt region (cnt dead after scan_a).
    char* p = (char*)d_ws;
    char* cnt_base = p;
    int* cnt = (int*)p;           p = align64(p + (size_t)NCNT * 4);          // 0.8 MB
    int* off = (int*)p;           p = align64(p + (size_t)OFF_PAD * 4);       // 0.8 MB
    int* aux = (int*)p;           p = align64(p + 256 * 4);
    unsigned* plist = (unsigned*)p; p = align64(p + (size_t)2 * N_EDGES * 4); // 12.8 MB
    ull* stg = (ull*)p;           p = align64(p + (size_t)2 * N_EDGES * 8);   // 25.6 MB
    _Float16* xh = (_Float16*)p;  p = align64(p + (size_t)N_NODES * D * 2);   // 25.6 MB
    int* bcur = (int*)p;          p = align64(p + (size_t)NB * 4);            // 3.2 KB
    // aliased into cnt region (total 384 KB < 800 KB):
    char* q = cnt_base;
    ushort_t* w0h = (ushort_t*)q;  q = align64(q + (size_t)128 * K0 * 2);
    ushort_t* w0l = (ushort_t*)q;  q = align64(q + (size_t)128 * K0 * 2);
    ushort_t* wlh = (ushort_t*)q;  q = align64(q + (size_t)3 * 128 * KL * 2);
    ushort_t* wll = (ushort_t*)q;

    (void)hipMemsetAsync(cnt, 0, NCNT * sizeof(int), stream);

    cvt_x_kernel<<<(N_NODES * D / 4) / 256, 256, 0, stream>>>(x, xh);
    hist_kernel<<<(N_EDGES + 255) / 256, 256, 0, stream>>>(sv, dv, cnt);
    scan_a<<<SCAN_BLOCKS, 256, 0, stream>>>(cnt, off, aux);
    scan_b<<<1, 256, 0, stream>>>(aux);
    scan_c<<<SCAN_BLOCKS, 256, 0, stream>>>(off, aux);
    binit<<<(NB + 255) / 256, 256, 0, stream>>>(off, bcur);

    // cnt is dead now; its region becomes the W-split buffers.
    wsplit0<<<(128 * K0 + 255) / 256, 256, 0, stream>>>(W0, w0h, w0l);
    wsplitL<<<(3 * 128 * KL + 255) / 256, 256, 0, stream>>>(W, wlh, wll);

    binpass<<<NBB, 256, 0, stream>>>(sv, dv, e, bcur, stg);
    scatpass<<<NB, 256, 0, stream>>>(stg, off, plist);

    layer0_fused<<<N_NODES / 16, 256, 0, stream>>>(xh, off, plist, x,
                                                   w0h, w0l, b0, g0, be0, out);

    layers123<<<N_NODES / 32, 256, 0, stream>>>(out, wlh, wll, b, g, be, out);
}

// Round 9
// 501.858 us; speedup vs baseline: 1.3155x; 1.2828x over previous
//
#include <hip/hip_runtime.h>
#include <math.h>

#define N_NODES 100000
#define N_EDGES 1600000
#define D 128
#define EPS 1e-5f
#define TASKS (2 * N_NODES)

#define K0 384
#define KL 128
#define PAD0 (K0 + 8)     // bf16 elems per LDS row, layer0
#define PADL (KL + 8)     // bf16 elems per LDS row, layers 1-3
#define SSTR 132          // f32 sout row stride

// --- bucketed fill (multisplit) ---
#define BSH 8                                    // 256 tasks per bucket
#define NB ((TASKS + 255) >> BSH)                // 782 buckets
#define CHUNKE 4096                              // edges per binpass block (round-2 proven)
#define NBB ((N_EDGES + CHUNKE - 1) / CHUNKE)    // 391 blocks
#define SCAP 6144                                // scatpass LDS image capacity

typedef unsigned short ushort_t;
typedef unsigned long long ull;
typedef short short8 __attribute__((ext_vector_type(8)));     // MFMA A/B frag
typedef _Float16 half8 __attribute__((ext_vector_type(8)));   // fp16 x row chunk
typedef _Float16 half4v __attribute__((ext_vector_type(4)));
typedef float f32x4 __attribute__((ext_vector_type(4)));      // MFMA C/D frag

static __device__ __forceinline__ float bf2f(ushort_t u) {
    return __uint_as_float(((unsigned)u) << 16);
}
static __device__ __forceinline__ ushort_t f2bf(float f) {
    unsigned u = __float_as_uint(f);
    u += 0x7FFF + ((u >> 16) & 1);          // RNE
    return (ushort_t)(u >> 16);
}
static __device__ __forceinline__ float tanh_fast(float v) {
    return 1.0f - 2.0f / (__expf(2.0f * v) + 1.0f);
}

// ---------------------------------------------------------------------------
// x (f32) -> xh (fp16), 4 elems/thread.
// ---------------------------------------------------------------------------
__global__ void cvt_x_kernel(const float* __restrict__ x, _Float16* __restrict__ xh) {
    int i = blockIdx.x * blockDim.x + threadIdx.x;   // 3.2M threads
    float4 v = ((const float4*)x)[i];
    half4v h;
    h[0] = (_Float16)v.x; h[1] = (_Float16)v.y;
    h[2] = (_Float16)v.z; h[3] = (_Float16)v.w;
    ((half4v*)xh)[i] = h;
}

// ---------------------------------------------------------------------------
// bhist: per-block LDS histogram over the 782 buckets, one global add per
// nonzero bucket. Replaces hist_kernel's 3.2M random global atomics over
// 800 KB + the 200K-element scan chain: per-task offsets are now derived
// inside scatpass (which reads every bucket entry anyway).
// ---------------------------------------------------------------------------
__global__ __launch_bounds__(256, 4) void bhist(
    const int* __restrict__ sv, const int* __restrict__ dv,
    int* __restrict__ btot) {
    __shared__ int hb[NB];
    int t = threadIdx.x;
    for (int i = t; i < NB; i += 256) hb[i] = 0;
    __syncthreads();
    int eb0 = blockIdx.x * CHUNKE;
    int ebn = N_EDGES - eb0;
    if (ebn > CHUNKE) ebn = CHUNKE;
#pragma unroll
    for (int i = 0; i < CHUNKE / 256; ++i) {
        int k = i * 256 + t;
        if (k < ebn) {
            int e = eb0 + k;
            atomicAdd(&hb[dv[e] >> BSH], 1);
            atomicAdd(&hb[(N_NODES + sv[e]) >> BSH], 1);
        }
    }
    __syncthreads();
    for (int i = t; i < NB; i += 256) {
        int h = hb[i];
        if (h) atomicAdd(&btot[i], h);
    }
}

// ---------------------------------------------------------------------------
// bscan: one block scans the 782 bucket totals -> boff[0..NB] and seeds
// bcur[b] = boff[b]. (Replaces scan_a/b/c + binit.)
// ---------------------------------------------------------------------------
__global__ void bscan(const int* __restrict__ btot, int* __restrict__ boff,
                      int* __restrict__ bcur) {
    __shared__ int partial[256];
    int t = threadIdx.x;
    int i0 = t * 4;
    int v0 = (i0 + 0 < NB) ? btot[i0 + 0] : 0;
    int v1 = (i0 + 1 < NB) ? btot[i0 + 1] : 0;
    int v2 = (i0 + 2 < NB) ? btot[i0 + 2] : 0;
    int v3 = (i0 + 3 < NB) ? btot[i0 + 3] : 0;
    int tot = v0 + v1 + v2 + v3;
    partial[t] = tot;
    __syncthreads();
    for (int s = 1; s < 256; s <<= 1) {
        int add = (t >= s) ? partial[t - s] : 0;
        __syncthreads();
        partial[t] += add;
        __syncthreads();
    }
    int excl = partial[t] - tot;
    int e0 = excl;
    int e1 = excl + v0;
    int e2 = excl + v0 + v1;
    int e3 = excl + v0 + v1 + v2;
    if (i0 + 0 < NB) { boff[i0 + 0] = e0; bcur[i0 + 0] = e0; }
    if (i0 + 1 < NB) { boff[i0 + 1] = e1; bcur[i0 + 1] = e1; }
    if (i0 + 2 < NB) { boff[i0 + 2] = e2; bcur[i0 + 2] = e2; }
    if (i0 + 3 < NB) { boff[i0 + 3] = e3; bcur[i0 + 3] = e3; }
    if (t == 255) boff[NB] = partial[255];
}

// ---------------------------------------------------------------------------
// binpass (round-2 proven config): bin entries into per-bucket regions of
// stg (8B entries: task<<32 | w15<<17 | other).
// ---------------------------------------------------------------------------
__global__ __launch_bounds__(256, 2) void binpass(
    const int* __restrict__ sv, const int* __restrict__ dv,
    const float* __restrict__ ew, int* __restrict__ bcur,
    ull* __restrict__ stg) {
    __shared__ ull image[2 * CHUNKE];          // 64 KB
    __shared__ int histB[NB];
    __shared__ int scB[NB];
    __shared__ int gbaseB[NB];
    __shared__ int partial[256];

    int t = threadIdx.x;
    int eb0 = blockIdx.x * CHUNKE;
    int ebn = N_EDGES - eb0;
    if (ebn > CHUNKE) ebn = CHUNKE;

    for (int i = t; i < NB; i += 256) histB[i] = 0;
    __syncthreads();

    // pass 1: histogram
#pragma unroll
    for (int i = 0; i < CHUNKE / 256; ++i) {
        int k = i * 256 + t;
        if (k < ebn) {
            int e = eb0 + k;
            int s = sv[e], d = dv[e];
            atomicAdd(&histB[d >> BSH], 1);
            atomicAdd(&histB[(N_NODES + s) >> BSH], 1);
        }
    }
    __syncthreads();

    // block exclusive scan of histB[0..NB) (pad to 1024, 4 elems/thread)
    {
        int i0 = t * 4;
        int v0 = (i0 + 0 < NB) ? histB[i0 + 0] : 0;
        int v1 = (i0 + 1 < NB) ? histB[i0 + 1] : 0;
        int v2 = (i0 + 2 < NB) ? histB[i0 + 2] : 0;
        int v3 = (i0 + 3 < NB) ? histB[i0 + 3] : 0;
        int tot = v0 + v1 + v2 + v3;
        partial[t] = tot;
        __syncthreads();
        for (int s = 1; s < 256; s <<= 1) {
            int add = (t >= s) ? partial[t - s] : 0;
            __syncthreads();
            partial[t] += add;
            __syncthreads();
        }
        int excl = partial[t] - tot;
        if (i0 + 0 < NB) scB[i0 + 0] = excl;
        if (i0 + 1 < NB) scB[i0 + 1] = excl + v0;
        if (i0 + 2 < NB) scB[i0 + 2] = excl + v0 + v1;
        if (i0 + 3 < NB) scB[i0 + 3] = excl + v0 + v1 + v2;
    }
    __syncthreads();

    // reserve global segments; reset histB for reuse as running counters
    for (int i = t; i < NB; i += 256) {
        int n = histB[i];
        gbaseB[i] = (n > 0) ? atomicAdd(&bcur[i], n) : 0;
        histB[i] = 0;
    }
    __syncthreads();

    // pass 2: scatter entries into LDS image in bucket order
#pragma unroll
    for (int i = 0; i < CHUNKE / 256; ++i) {
        int k = i * 256 + t;
        if (k < ebn) {
            int e = eb0 + k;
            int s = sv[e], d = dv[e];
            float w = ew[e];
            unsigned wq = (unsigned)(w * 32768.0f + 0.5f);
            if (wq > 32767u) wq = 32767u;
            // mi entry: task = d, payload = s
            {
                int task = d, b = task >> BSH;
                int l = atomicAdd(&histB[b], 1);
                image[scB[b] + l] = ((ull)task << 32) | ((ull)wq << 17) | (ull)(unsigned)s;
            }
            // mo entry: task = N_NODES + s, payload = d
            {
                int task = N_NODES + s, b = task >> BSH;
                int l = atomicAdd(&histB[b], 1);
                image[scB[b] + l] = ((ull)task << 32) | ((ull)wq << 17) | (ull)(unsigned)d;
            }
        }
    }
    __syncthreads();

    // write-out: consecutive LDS positions -> consecutive global addresses
    int nE = 2 * ebn;
    for (int p = t; p < nE; p += 256) {
        ull en = image[p];
        int task = (int)(en >> 32);
        int b = task >> BSH;
        stg[(size_t)gbaseB[b] + (p - scB[b])] = en;
    }
}

// ---------------------------------------------------------------------------
// scatpass: per bucket, count per-task entries (LDS), scan 256 locally,
// WRITE the per-task off[] (consumed by the fused gather), then place
// payloads to final CSR order in LDS and write plist out coalesced.
// ---------------------------------------------------------------------------
__global__ __launch_bounds__(256, 2) void scatpass(
    const ull* __restrict__ stg, const int* __restrict__ boff,
    int* __restrict__ off, unsigned* __restrict__ plist) {
    __shared__ unsigned img[SCAP];             // 24 KB
    __shared__ int lcnt[256];
    __shared__ int ltoff[256];
    __shared__ int partial[256];

    int t = threadIdx.x;
    int b = blockIdx.x;
    int t0 = b << BSH;
    int tl = TASKS - t0;
    if (tl > 256) tl = 256;
    int s0 = boff[b];
    int s1 = boff[b + 1];
    int n = s1 - s0;

    lcnt[t] = 0;
    __syncthreads();

    // pass 1: per-task counts
    for (int p = t; p < n; p += 256) {
        ull en = stg[(size_t)s0 + p];
        int lt = (int)(en >> 32) - t0;
        atomicAdd(&lcnt[lt], 1);
    }
    __syncthreads();

    // local exclusive scan of 256 task counts
    int v = lcnt[t];
    partial[t] = v;
    __syncthreads();
    for (int s = 1; s < 256; s <<= 1) {
        int add = (t >= s) ? partial[t - s] : 0;
        __syncthreads();
        partial[t] += add;
        __syncthreads();
    }
    int excl = partial[t] - v;
    ltoff[t] = excl;
    if (t < tl) off[t0 + t] = s0 + excl;
    if (b == NB - 1 && t == 0) off[TASKS] = s1;
    lcnt[t] = 0;                 // reuse as running cursors
    __syncthreads();

    if (n <= SCAP) {
        for (int p = t; p < n; p += 256) {
            ull en = stg[(size_t)s0 + p];
            int lt = (int)(en >> 32) - t0;
            int l = atomicAdd(&lcnt[lt], 1);
            img[ltoff[lt] + l] = (unsigned)(en & 0xFFFFFFFFull);
        }
        __syncthreads();
        for (int p = t; p < n; p += 256)
            plist[s0 + p] = img[p];
    } else {
        // statistically unreachable fallback: direct global scatter.
        for (int p = t; p < n; p += 256) {
            ull en = stg[(size_t)s0 + p];
            int lt = (int)(en >> 32) - t0;
            int l = atomicAdd(&lcnt[lt], 1);
            plist[(size_t)s0 + ltoff[lt] + l] = (unsigned)(en & 0xFFFFFFFFull);
        }
    }
}

// ---------------------------------------------------------------------------
// Weight transpose + hi/lo bf16 split (Wt[n][k] layout).
// ---------------------------------------------------------------------------
__global__ void wsplit0(const float* __restrict__ W0, ushort_t* __restrict__ hi,
                        ushort_t* __restrict__ lo) {
    int id = blockIdx.x * 256 + threadIdx.x;     // 128*384
    if (id >= 128 * K0) return;
    int n = id / K0, k = id % K0;
    float a = W0[k * 128 + n];
    ushort_t h = f2bf(a);
    hi[id] = h;
    lo[id] = f2bf(a - bf2f(h));
}

__global__ void wsplitL(const float* __restrict__ W, ushort_t* __restrict__ hi,
                        ushort_t* __restrict__ lo) {
    int id = blockIdx.x * 256 + threadIdx.x;     // 3*128*128
    if (id >= 3 * 128 * KL) return;
    int l = id / (128 * KL), r = id % (128 * KL);
    int n = r / KL, k = r % KL;
    float a = W[l * 128 * KL + k * 128 + n];
    ushort_t h = f2bf(a);
    hi[id] = h;
    lo[id] = f2bf(a - bf2f(h));
}

// ---------------------------------------------------------------------------
// FUSED gather + layer0 (R6 proven config: single-task wave loop,
// launch_bounds(256,6), red/smv aliased into Alo).
// ---------------------------------------------------------------------------
__global__ __launch_bounds__(256, 6) void layer0_fused(
    const _Float16* __restrict__ xh, const int* __restrict__ off,
    const unsigned* __restrict__ plist, const float* __restrict__ x,
    const ushort_t* __restrict__ Bh, const ushort_t* __restrict__ Bl,
    const float* __restrict__ b0, const float* __restrict__ g0,
    const float* __restrict__ be0, float* __restrict__ h) {
    __shared__ __align__(16) char smem[2 * 16 * PAD0 * 2];   // 25088 B total
    ushort_t* Ahi = (ushort_t*)smem;
    ushort_t* Alo = Ahi + 16 * PAD0;
    float* sout = (float*)smem;                        // aliases Ahi (8448 B)
    float* red  = (float*)(smem + 16 * PAD0 * 2);      // aliases Alo (2048 B)
    float* smv  = red + 16 * 16 * 2;                   // aliases Alo (+128 B)

    int t = threadIdx.x;
    int node0 = blockIdx.x * 16;
    int lane = t & 63, wv = t >> 6;
    int g = lane >> 4, i15 = lane & 15;
    const float wsc = 1.0f / 32768.0f;

    // stage x section (cols 256..383): 16 rows x 32 float4
#pragma unroll
    for (int it = 0; it < 2; ++it) {
        int id = it * 256 + t;
        int r = id >> 5;
        int c = 256 + (id & 31) * 4;
        float4 v = *(const float4*)&x[(size_t)(node0 + r) * D + (c - 256)];
        ushort_t h0 = f2bf(v.x), h1 = f2bf(v.y), h2 = f2bf(v.z), h3 = f2bf(v.w);
        ushort_t l0 = f2bf(v.x - bf2f(h0)), l1 = f2bf(v.y - bf2f(h1));
        ushort_t l2 = f2bf(v.z - bf2f(h2)), l3 = f2bf(v.w - bf2f(h3));
        *(ull*)&Ahi[r * PAD0 + c] = (ull)h0 | ((ull)h1 << 16) | ((ull)h2 << 32) | ((ull)h3 << 48);
        *(ull*)&Alo[r * PAD0 + c] = (ull)l0 | ((ull)l1 << 16) | ((ull)l2 << 32) | ((ull)l3 << 48);
    }

    // gather phase: 32 tasks (16 mi + 16 mo), 8 per wave, one wave per task
    for (int rep = 0; rep < 8; ++rep) {
        int k = wv * 8 + rep;                 // 0..31
        int row = k & 15;
        int cb = (k < 16) ? 0 : 128;
        int task = (k < 16) ? (node0 + k) : (N_NODES + node0 + (k - 16));
        int e0 = off[task], e1 = off[task + 1];

        float acc[8];
#pragma unroll
        for (int r = 0; r < 8; ++r) acc[r] = 0.f;

        for (int base = e0; base < e1; base += 64) {
            unsigned pv = 0;
            int idx = base + lane;
            if (idx < e1) pv = plist[idx];
            int cnt = e1 - base;
            if (cnt > 64) cnt = 64;
            int jn = (cnt + 3) >> 2;
            int j = 0;
            for (; j + 3 < jn; j += 4) {
                unsigned p0 = (unsigned)__shfl((int)pv, (j + 0) * 4 + g);
                unsigned p1 = (unsigned)__shfl((int)pv, (j + 1) * 4 + g);
                unsigned p2 = (unsigned)__shfl((int)pv, (j + 2) * 4 + g);
                unsigned p3 = (unsigned)__shfl((int)pv, (j + 3) * 4 + g);
                half8 v0 = *(const half8*)(xh + (size_t)(p0 & 0x1FFFF) * D + i15 * 8);
                half8 v1 = *(const half8*)(xh + (size_t)(p1 & 0x1FFFF) * D + i15 * 8);
                half8 v2 = *(const half8*)(xh + (size_t)(p2 & 0x1FFFF) * D + i15 * 8);
                half8 v3 = *(const half8*)(xh + (size_t)(p3 & 0x1FFFF) * D + i15 * 8);
                float w0 = (float)(p0 >> 17) * wsc;
                float w1 = (float)(p1 >> 17) * wsc;
                float w2 = (float)(p2 >> 17) * wsc;
                float w3 = (float)(p3 >> 17) * wsc;
#pragma unroll
                for (int r = 0; r < 8; ++r) acc[r] = fmaf(w0, (float)v0[r], acc[r]);
#pragma unroll
                for (int r = 0; r < 8; ++r) acc[r] = fmaf(w1, (float)v1[r], acc[r]);
#pragma unroll
                for (int r = 0; r < 8; ++r) acc[r] = fmaf(w2, (float)v2[r], acc[r]);
#pragma unroll
                for (int r = 0; r < 8; ++r) acc[r] = fmaf(w3, (float)v3[r], acc[r]);
            }
            for (; j < jn; ++j) {
                unsigned p0 = (unsigned)__shfl((int)pv, j * 4 + g);
                half8 v0 = *(const half8*)(xh + (size_t)(p0 & 0x1FFFF) * D + i15 * 8);
                float w0 = (float)(p0 >> 17) * wsc;
#pragma unroll
                for (int r = 0; r < 8; ++r) acc[r] = fmaf(w0, (float)v0[r], acc[r]);
            }
        }

#pragma unroll
        for (int r = 0; r < 8; ++r) {
            acc[r] += __shfl_xor(acc[r], 32);
            acc[r] += __shfl_xor(acc[r], 16);
        }
        if (g == 0) {
            ushort_t hh[8], ll[8];
#pragma unroll
            for (int r = 0; r < 8; ++r) {
                hh[r] = f2bf(acc[r]);
                ll[r] = f2bf(acc[r] - bf2f(hh[r]));
            }
            int cc = cb + i15 * 8;
            *(ull*)&Ahi[row * PAD0 + cc] =
                (ull)hh[0] | ((ull)hh[1] << 16) | ((ull)hh[2] << 32) | ((ull)hh[3] << 48);
            *(ull*)&Ahi[row * PAD0 + cc + 4] =
                (ull)hh[4] | ((ull)hh[5] << 16) | ((ull)hh[6] << 32) | ((ull)hh[7] << 48);
            *(ull*)&Alo[row * PAD0 + cc] =
                (ull)ll[0] | ((ull)ll[1] << 16) | ((ull)ll[2] << 32) | ((ull)ll[3] << 48);
            *(ull*)&Alo[row * PAD0 + cc + 4] =
                (ull)ll[4] | ((ull)ll[5] << 16) | ((ull)ll[6] << 32) | ((ull)ll[7] << 48);
        }
    }
    __syncthreads();

    // MFMA phase: M=16, N=128 (4 waves x 32 cols), K=384
    int quad = lane >> 4, m15 = lane & 15;
    int cw = wv * 32;

    f32x4 acc2[2];
    acc2[0] = (f32x4)0.f;
    acc2[1] = (f32x4)0.f;

    for (int k0 = 0; k0 < K0; k0 += 32) {
        int ka = k0 + quad * 8;
        short8 ah = *(const short8*)&Ahi[m15 * PAD0 + ka];
        short8 al = *(const short8*)&Alo[m15 * PAD0 + ka];
        short8 bh0 = *(const short8*)(Bh + (size_t)(cw + m15) * K0 + ka);
        short8 bh1 = *(const short8*)(Bh + (size_t)(cw + 16 + m15) * K0 + ka);
        short8 bl0 = *(const short8*)(Bl + (size_t)(cw + m15) * K0 + ka);
        short8 bl1 = *(const short8*)(Bl + (size_t)(cw + 16 + m15) * K0 + ka);
        acc2[0] = __builtin_amdgcn_mfma_f32_16x16x32_bf16(ah, bh0, acc2[0], 0, 0, 0);
        acc2[1] = __builtin_amdgcn_mfma_f32_16x16x32_bf16(ah, bh1, acc2[1], 0, 0, 0);
        acc2[0] = __builtin_amdgcn_mfma_f32_16x16x32_bf16(al, bh0, acc2[0], 0, 0, 0);
        acc2[1] = __builtin_amdgcn_mfma_f32_16x16x32_bf16(al, bh1, acc2[1], 0, 0, 0);
        acc2[0] = __builtin_amdgcn_mfma_f32_16x16x32_bf16(ah, bl0, acc2[0], 0, 0, 0);
        acc2[1] = __builtin_amdgcn_mfma_f32_16x16x32_bf16(ah, bl1, acc2[1], 0, 0, 0);
    }
    __syncthreads();

    float bc0 = b0[cw + m15], bc1 = b0[cw + 16 + m15];
#pragma unroll
    for (int ct = 0; ct < 2; ++ct) {
        float bc = ct ? bc1 : bc0;
        int col = cw + ct * 16 + m15;
#pragma unroll
        for (int reg = 0; reg < 4; ++reg) {
            int row = quad * 4 + reg;
            sout[row * SSTR + col] = acc2[ct][reg] + bc;
        }
    }
    __syncthreads();

    {
        int r = t >> 4, p = t & 15;
        float s = 0.f, s2 = 0.f;
        for (int c = p * 8; c < p * 8 + 8; ++c) {
            float v = sout[r * SSTR + c];
            s += v; s2 += v * v;
        }
        red[(r * 16 + p) * 2 + 0] = s;
        red[(r * 16 + p) * 2 + 1] = s2;
    }
    __syncthreads();
    if (t < 16) {
        float ss = 0.f, ss2 = 0.f;
#pragma unroll
        for (int q = 0; q < 16; ++q) {
            ss += red[(t * 16 + q) * 2 + 0];
            ss2 += red[(t * 16 + q) * 2 + 1];
        }
        float m = ss * (1.0f / D);
        float var = ss2 * (1.0f / D) - m * m;
        smv[t * 2 + 0] = m;
        smv[t * 2 + 1] = rsqrtf(var + EPS);
    }
    __syncthreads();

#pragma unroll
    for (int pass = 0; pass < 2; ++pass) {
        int id = pass * 256 + t;
        int r = id >> 5;
        int c = (id & 31) * 4;
        float mm = smv[r * 2 + 0], rs = smv[r * 2 + 1];
        float4 sv = *(const float4*)&sout[r * SSTR + c];
        float4 gv = *(const float4*)&g0[c];
        float4 bv = *(const float4*)&be0[c];
        float4 o;
        o.x = tanh_fast((sv.x - mm) * rs * gv.x + bv.x);
        o.y = tanh_fast((sv.y - mm) * rs * gv.y + bv.y);
        o.z = tanh_fast((sv.z - mm) * rs * gv.z + bv.z);
        o.w = tanh_fast((sv.w - mm) * rs * gv.w + bv.w);
        *(float4*)&h[(size_t)(node0 + r) * D + c] = o;
    }
}

// ---------------------------------------------------------------------------
// FUSED layers 1..3: h = tanh(LN(h @ W_l + b_l)) applied 3x entirely in LDS.
// ---------------------------------------------------------------------------
__global__ __launch_bounds__(256, 4) void layers123(
    const float* hin,
    const ushort_t* __restrict__ Bh, const ushort_t* __restrict__ Bl,
    const float* __restrict__ b, const float* __restrict__ g,
    const float* __restrict__ be, float* hout) {
    __shared__ __align__(16) ushort_t Ahi[32 * PADL];
    __shared__ __align__(16) ushort_t Alo[32 * PADL];
    __shared__ __align__(16) float sout[32 * SSTR];
    __shared__ float red[32][8][2];
    __shared__ float smv[32][2];

    int t = threadIdx.x;
    int node0 = blockIdx.x * 32;

    // stage h -> A-tile (bf16 hi/lo)
#pragma unroll
    for (int i = 0; i < 4; ++i) {
        int id = i * 256 + t;
        int r = id >> 5;
        int c = (id & 31) * 4;
        float4 v = *(const float4*)&hin[(size_t)(node0 + r) * D + c];
        ushort_t h0 = f2bf(v.x), h1 = f2bf(v.y), h2 = f2bf(v.z), h3 = f2bf(v.w);
        ushort_t l0 = f2bf(v.x - bf2f(h0)), l1 = f2bf(v.y - bf2f(h1));
        ushort_t l2 = f2bf(v.z - bf2f(h2)), l3 = f2bf(v.w - bf2f(h3));
        *(ull*)&Ahi[r * PADL + c] = (ull)h0 | ((ull)h1 << 16) | ((ull)h2 << 32) | ((ull)h3 << 48);
        *(ull*)&Alo[r * PADL + c] = (ull)l0 | ((ull)l1 << 16) | ((ull)l2 << 32) | ((ull)l3 << 48);
    }

    int lane = t & 63, wv = t >> 6;
    int quad = lane >> 4, m15 = lane & 15;
    int cw = wv * 32;

    for (int l = 0; l < 3; ++l) {
        const ushort_t* Bhl = Bh + (size_t)l * 128 * KL;
        const ushort_t* Bll = Bl + (size_t)l * 128 * KL;
        __syncthreads();   // A-tile ready (staging or previous write-back)

        f32x4 acc[2][2];
#pragma unroll
        for (int rt = 0; rt < 2; ++rt)
#pragma unroll
            for (int ct = 0; ct < 2; ++ct) acc[rt][ct] = (f32x4)0.f;

#pragma unroll
        for (int k0 = 0; k0 < KL; k0 += 32) {
            int ka = k0 + quad * 8;
            short8 ah0 = *(const short8*)&Ahi[(m15) * PADL + ka];
            short8 ah1 = *(const short8*)&Ahi[(16 + m15) * PADL + ka];
            short8 al0 = *(const short8*)&Alo[(m15) * PADL + ka];
            short8 al1 = *(const short8*)&Alo[(16 + m15) * PADL + ka];
            short8 bh0 = *(const short8*)(Bhl + (size_t)(cw + m15) * KL + ka);
            short8 bh1 = *(const short8*)(Bhl + (size_t)(cw + 16 + m15) * KL + ka);
            short8 bl0 = *(const short8*)(Bll + (size_t)(cw + m15) * KL + ka);
            short8 bl1 = *(const short8*)(Bll + (size_t)(cw + 16 + m15) * KL + ka);
            acc[0][0] = __builtin_amdgcn_mfma_f32_16x16x32_bf16(ah0, bh0, acc[0][0], 0, 0, 0);
            acc[0][1] = __builtin_amdgcn_mfma_f32_16x16x32_bf16(ah0, bh1, acc[0][1], 0, 0, 0);
            acc[1][0] = __builtin_amdgcn_mfma_f32_16x16x32_bf16(ah1, bh0, acc[1][0], 0, 0, 0);
            acc[1][1] = __builtin_amdgcn_mfma_f32_16x16x32_bf16(ah1, bh1, acc[1][1], 0, 0, 0);
            acc[0][0] = __builtin_amdgcn_mfma_f32_16x16x32_bf16(al0, bh0, acc[0][0], 0, 0, 0);
            acc[0][1] = __builtin_amdgcn_mfma_f32_16x16x32_bf16(al0, bh1, acc[0][1], 0, 0, 0);
            acc[1][0] = __builtin_amdgcn_mfma_f32_16x16x32_bf16(al1, bh0, acc[1][0], 0, 0, 0);
            acc[1][1] = __builtin_amdgcn_mfma_f32_16x16x32_bf16(al1, bh1, acc[1][1], 0, 0, 0);
            acc[0][0] = __builtin_amdgcn_mfma_f32_16x16x32_bf16(ah0, bl0, acc[0][0], 0, 0, 0);
            acc[0][1] = __builtin_amdgcn_mfma_f32_16x16x32_bf16(ah0, bl1, acc[0][1], 0, 0, 0);
            acc[1][0] = __builtin_amdgcn_mfma_f32_16x16x32_bf16(ah1, bl0, acc[1][0], 0, 0, 0);
            acc[1][1] = __builtin_amdgcn_mfma_f32_16x16x32_bf16(ah1, bl1, acc[1][1], 0, 0, 0);
        }

        float bc0 = b[l * D + cw + m15], bc1 = b[l * D + cw + 16 + m15];
#pragma unroll
        for (int rt = 0; rt < 2; ++rt)
#pragma unroll
            for (int ct = 0; ct < 2; ++ct) {
                float bc = ct ? bc1 : bc0;
                int col = cw + ct * 16 + m15;
#pragma unroll
                for (int reg = 0; reg < 4; ++reg) {
                    int row = rt * 16 + quad * 4 + reg;
                    sout[row * SSTR + col] = acc[rt][ct][reg] + bc;
                }
            }
        __syncthreads();

        {
            int r = t >> 3, p = t & 7;
            float s = 0.f, s2 = 0.f;
            for (int c = p * 16; c < p * 16 + 16; ++c) {
                float v = sout[r * SSTR + c];
                s += v; s2 += v * v;
            }
            red[r][p][0] = s; red[r][p][1] = s2;
        }
        __syncthreads();
        if (t < 32) {
            float ss = 0.f, ss2 = 0.f;
#pragma unroll
            for (int q = 0; q < 8; ++q) { ss += red[t][q][0]; ss2 += red[t][q][1]; }
            float m = ss * (1.0f / D);
            float var = ss2 * (1.0f / D) - m * m;
            smv[t][0] = m;
            smv[t][1] = rsqrtf(var + EPS);
        }
        __syncthreads();

#pragma unroll
        for (int pass = 0; pass < 4; ++pass) {
            int r = pass * 8 + (t >> 5);
            int c = (t & 31) * 4;
            float mm = smv[r][0], rs = smv[r][1];
            float4 sv = *(const float4*)&sout[r * SSTR + c];
            float4 gv = *(const float4*)&g[l * D + c];
            float4 bv = *(const float4*)&be[l * D + c];
            float o0 = tanh_fast((sv.x - mm) * rs * gv.x + bv.x);
            float o1 = tanh_fast((sv.y - mm) * rs * gv.y + bv.y);
            float o2 = tanh_fast((sv.z - mm) * rs * gv.z + bv.z);
            float o3 = tanh_fast((sv.w - mm) * rs * gv.w + bv.w);
            if (l < 2) {
                ushort_t h0 = f2bf(o0), h1 = f2bf(o1), h2 = f2bf(o2), h3 = f2bf(o3);
                ushort_t l0 = f2bf(o0 - bf2f(h0)), l1 = f2bf(o1 - bf2f(h1));
                ushort_t l2 = f2bf(o2 - bf2f(h2)), l3 = f2bf(o3 - bf2f(h3));
                *(ull*)&Ahi[r * PADL + c] = (ull)h0 | ((ull)h1 << 16) | ((ull)h2 << 32) | ((ull)h3 << 48);
                *(ull*)&Alo[r * PADL + c] = (ull)l0 | ((ull)l1 << 16) | ((ull)l2 << 32) | ((ull)l3 << 48);
            } else {
                *(float4*)&hout[(size_t)(node0 + r) * D + c] =
                    make_float4(o0, o1, o2, o3);
            }
        }
    }
}

static inline char* align64(char* p) {
    return (char*)(((uintptr_t)p + 63) & ~(uintptr_t)63);
}

extern "C" void kernel_launch(void* const* d_in, const int* in_sizes, int n_in,
                              void* d_out, int out_size, void* d_ws, size_t ws_size,
                              hipStream_t stream) {
    const float* x   = (const float*)d_in[0];
    const float* e   = (const float*)d_in[1];
    const int*   ei  = (const int*)d_in[2];
    const float* W0  = (const float*)d_in[3];
    const float* b0  = (const float*)d_in[4];
    const float* g0  = (const float*)d_in[5];
    const float* be0 = (const float*)d_in[6];
    const float* W   = (const float*)d_in[7];
    const float* b   = (const float*)d_in[8];
    const float* g   = (const float*)d_in[9];
    const float* be  = (const float*)d_in[10];
    float* out = (float*)d_out;

    const int* sv = ei;              // edge_index[0] = start
    const int* dv = ei + N_EDGES;    // edge_index[1] = end

    // workspace (~66 MB). No aliasing needed any more: the old cnt region
    // is gone (hist/scan chain replaced by bucket-level bhist/bscan +
    // per-task offsets derived inside scatpass).
    char* p = (char*)d_ws;
    ushort_t* w0h = (ushort_t*)p;  p = align64(p + (size_t)128 * K0 * 2);
    ushort_t* w0l = (ushort_t*)p;  p = align64(p + (size_t)128 * K0 * 2);
    ushort_t* wlh = (ushort_t*)p;  p = align64(p + (size_t)3 * 128 * KL * 2);
    ushort_t* wll = (ushort_t*)p;  p = align64(p + (size_t)3 * 128 * KL * 2);
    int* off  = (int*)p;           p = align64(p + (size_t)(TASKS + 1) * 4);  // 0.8 MB
    int* btot = (int*)p;           p = align64(p + (size_t)NB * 4);
    int* boff = (int*)p;           p = align64(p + (size_t)(NB + 1) * 4);
    int* bcur = (int*)p;           p = align64(p + (size_t)NB * 4);
    unsigned* plist = (unsigned*)p; p = align64(p + (size_t)2 * N_EDGES * 4); // 12.8 MB
    ull* stg = (ull*)p;            p = align64(p + (size_t)2 * N_EDGES * 8);  // 25.6 MB
    _Float16* xh = (_Float16*)p;   p = align64(p + (size_t)N_NODES * D * 2);  // 25.6 MB

    (void)hipMemsetAsync(btot, 0, NB * sizeof(int), stream);

    cvt_x_kernel<<<(N_NODES * D / 4) / 256, 256, 0, stream>>>(x, xh);
    bhist<<<NBB, 256, 0, stream>>>(sv, dv, btot);
    bscan<<<1, 256, 0, stream>>>(btot, boff, bcur);

    wsplit0<<<(128 * K0 + 255) / 256, 256, 0, stream>>>(W0, w0h, w0l);
    wsplitL<<<(3 * 128 * KL + 255) / 256, 256, 0, stream>>>(W, wlh, wll);

    binpass<<<NBB, 256, 0, stream>>>(sv, dv, e, bcur, stg);
    scatpass<<<NB, 256, 0, stream>>>(stg, boff, off, plist);

    layer0_fused<<<N_NODES / 16, 256, 0, stream>>>(xh, off, plist, x,
                                                   w0h, w0l, b0, g0, be0, out);

    layers123<<<N_NODES / 32, 256, 0, stream>>>(out, wlh, wll, b, g, be, out);
}